// Round 10
// baseline (189.249 us; speedup 1.0000x reference)
//
#include <hip/hip_runtime.h>
#include <math.h>

#define NBb  16
#define NOPc 512
#define NMAc 64
#define HIDc 256
#define OUTc 128
#define NROW (NBb * NOPc)          // 8192 (b,i) rows
#define NEMAX (NROW * NMAc)        // 524288 max edges

typedef unsigned int uint32;
typedef unsigned short ush;
typedef __attribute__((ext_vector_type(8))) short bf16x8;
typedef __attribute__((ext_vector_type(4))) float f32x4;

__device__ __forceinline__ ush f2bf(float v) {
    uint32 u = __float_as_uint(v);
    u += 0x7FFFu + ((u >> 16) & 1u);
    return (ush)(u >> 16);
}
__device__ __forceinline__ float bf2f(ush b) { return __uint_as_float(((uint32)b) << 16); }
__device__ __forceinline__ float eluf(float x) { return x > 0.f ? x : expm1f(x); }
__device__ __forceinline__ float eluf_fast(float x) { return x > 0.f ? x : __expf(x) - 1.f; }
// pack two floats' truncated bf16 into one u32: low = bf16(a), high = bf16(b)
__device__ __forceinline__ uint32 pkbf(float a, float b) {
    return __builtin_amdgcn_perm(__float_as_uint(b), __float_as_uint(a), 0x07060302u);
}
__device__ __forceinline__ uint32 pkbf_rne(float a, float b) {
    return (uint32)f2bf(a) | ((uint32)f2bf(b) << 16);
}
// truncation hi/lo split of 2 floats (residual captured exactly by lo plane)
__device__ __forceinline__ void split2(float a, float b, uint32& hp, uint32& lp) {
    const uint32 ua = __float_as_uint(a), ub = __float_as_uint(b);
    hp = __builtin_amdgcn_perm(ub, ua, 0x07060302u);
    const float ra = a - __uint_as_float(ua & 0xFFFF0000u);
    const float rb = b - __uint_as_float(ub & 0xFFFF0000u);
    lp = __builtin_amdgcn_perm(__float_as_uint(rb), __float_as_uint(ra), 0x07060302u);
}

#define MFMA(A, B, C) __builtin_amdgcn_mfma_f32_16x16x32_bf16((A), (B), (C), 0, 0, 0)

// pack[((kb*nbn + nb)*64 + lane)*8 + e] = W[kb*32 + 8*(lane>>4) + e][nb*16 + (lane&15)]
struct MlpPack {
    const ush *w1h, *w1l, *w2h, *w2l, *w3h, *w3l;
    const float *b1, *b2, *b3;
};

// ---------------------------------------------------------------------------
// Hi/lo (bf16x3) 3-layer core over a 32-row tile (pre/sub/self/MLP4 paths).
// ---------------------------------------------------------------------------
__device__ __forceinline__ void mlp3_core32(
    const MlpPack& P, const int KB1,
    const ush* Xh, const ush* Xl, ush* Hh, ush* Hl, f32x4 acc3[2][2])
{
    const int tid = threadIdx.x;
    const int wv = tid >> 6, lane = tid & 63, r = lane & 15, g = lane >> 4;
    const int KX = KB1 * 32;

    // layer 1: KX -> 256
    {
        f32x4 acc[4][2];
        #pragma unroll
        for (int a = 0; a < 4; ++a)
            #pragma unroll
            for (int m = 0; m < 2; ++m) acc[a][m] = f32x4{0.f, 0.f, 0.f, 0.f};
        #pragma unroll 1
        for (int kb = 0; kb < KB1; ++kb) {
            bf16x8 wh[4], wl[4];
            #pragma unroll
            for (int a = 0; a < 4; ++a) {
                const size_t o = ((size_t)(kb * 16 + (wv * 4 + a)) * 64 + lane) * 8;
                wh[a] = *(const bf16x8*)(P.w1h + o);
                wl[a] = *(const bf16x8*)(P.w1l + o);
            }
            #pragma unroll
            for (int m = 0; m < 2; ++m) {
                const int row = 16 * m + r;
                const int ki = kb * 32 + 8 * g;
                bf16x8 xh = *(const bf16x8*)(Xh + row * KX + ki);
                bf16x8 xl = *(const bf16x8*)(Xl + row * KX + ki);
                #pragma unroll
                for (int a = 0; a < 4; ++a) {
                    acc[a][m] = MFMA(wh[a], xh, acc[a][m]);
                    acc[a][m] = MFMA(wh[a], xl, acc[a][m]);
                    acc[a][m] = MFMA(wl[a], xh, acc[a][m]);
                }
            }
        }
        #pragma unroll
        for (int a = 0; a < 4; ++a) {
            const int n0 = (wv * 4 + a) * 16 + 4 * g;
            const float4 bv = *(const float4*)(P.b1 + n0);
            #pragma unroll
            for (int m = 0; m < 2; ++m) {
                const int row = 16 * m + r;
                const float y0 = eluf_fast(acc[a][m][0] + bv.x);
                const float y1 = eluf_fast(acc[a][m][1] + bv.y);
                const float y2 = eluf_fast(acc[a][m][2] + bv.z);
                const float y3 = eluf_fast(acc[a][m][3] + bv.w);
                uint2 uh, ul;
                split2(y0, y1, uh.x, ul.x);
                split2(y2, y3, uh.y, ul.y);
                const int idx = row * 256 + (n0 ^ (8 * (row & 7)));
                *(uint2*)(Hh + idx) = uh;
                *(uint2*)(Hl + idx) = ul;
            }
        }
    }
    __syncthreads();

    // layer 2: 256 -> 256 (in place)
    {
        f32x4 acc[4][2];
        #pragma unroll
        for (int a = 0; a < 4; ++a)
            #pragma unroll
            for (int m = 0; m < 2; ++m) acc[a][m] = f32x4{0.f, 0.f, 0.f, 0.f};
        #pragma unroll 1
        for (int kb = 0; kb < 8; ++kb) {
            bf16x8 wh[4], wl[4];
            #pragma unroll
            for (int a = 0; a < 4; ++a) {
                const size_t o = ((size_t)(kb * 16 + (wv * 4 + a)) * 64 + lane) * 8;
                wh[a] = *(const bf16x8*)(P.w2h + o);
                wl[a] = *(const bf16x8*)(P.w2l + o);
            }
            #pragma unroll
            for (int m = 0; m < 2; ++m) {
                const int row = 16 * m + r;
                const int k0 = kb * 32 + 8 * g;
                const int idx = row * 256 + (k0 ^ (8 * (row & 7)));
                bf16x8 hh = *(const bf16x8*)(Hh + idx);
                bf16x8 hl = *(const bf16x8*)(Hl + idx);
                #pragma unroll
                for (int a = 0; a < 4; ++a) {
                    acc[a][m] = MFMA(wh[a], hh, acc[a][m]);
                    acc[a][m] = MFMA(wh[a], hl, acc[a][m]);
                    acc[a][m] = MFMA(wl[a], hh, acc[a][m]);
                }
            }
        }
        __syncthreads();
        #pragma unroll
        for (int a = 0; a < 4; ++a) {
            const int n0 = (wv * 4 + a) * 16 + 4 * g;
            const float4 bv = *(const float4*)(P.b2 + n0);
            #pragma unroll
            for (int m = 0; m < 2; ++m) {
                const int row = 16 * m + r;
                const float y0 = eluf_fast(acc[a][m][0] + bv.x);
                const float y1 = eluf_fast(acc[a][m][1] + bv.y);
                const float y2 = eluf_fast(acc[a][m][2] + bv.z);
                const float y3 = eluf_fast(acc[a][m][3] + bv.w);
                uint2 uh, ul;
                split2(y0, y1, uh.x, ul.x);
                split2(y2, y3, uh.y, ul.y);
                const int idx = row * 256 + (n0 ^ (8 * (row & 7)));
                *(uint2*)(Hh + idx) = uh;
                *(uint2*)(Hl + idx) = ul;
            }
        }
    }
    __syncthreads();

    // layer 3: 256 -> 128
    {
        #pragma unroll
        for (int a = 0; a < 2; ++a)
            #pragma unroll
            for (int m = 0; m < 2; ++m) acc3[a][m] = f32x4{0.f, 0.f, 0.f, 0.f};
        #pragma unroll 1
        for (int kb = 0; kb < 8; ++kb) {
            bf16x8 wh[2], wl[2];
            #pragma unroll
            for (int a = 0; a < 2; ++a) {
                const size_t o = ((size_t)(kb * 8 + (wv * 2 + a)) * 64 + lane) * 8;
                wh[a] = *(const bf16x8*)(P.w3h + o);
                wl[a] = *(const bf16x8*)(P.w3l + o);
            }
            #pragma unroll
            for (int m = 0; m < 2; ++m) {
                const int row = 16 * m + r;
                const int k0 = kb * 32 + 8 * g;
                const int idx = row * 256 + (k0 ^ (8 * (row & 7)));
                bf16x8 hh = *(const bf16x8*)(Hh + idx);
                bf16x8 hl = *(const bf16x8*)(Hl + idx);
                #pragma unroll
                for (int a = 0; a < 2; ++a) {
                    acc3[a][m] = MFMA(wh[a], hh, acc3[a][m]);
                    acc3[a][m] = MFMA(wh[a], hl, acc3[a][m]);
                    acc3[a][m] = MFMA(wl[a], hh, acc3[a][m]);
                }
            }
        }
    }
}

// ---------------------------------------------------------------------------
// prep: pack (blocks [0,960)) + agg/ma-count ([960,9152)) + f1z (last).
// ---------------------------------------------------------------------------
struct PackDesc { const float* src; ush* dh; ush* dl; int kreal; int kbn; int nbn; };
struct PrepArgs {
    PackDesc d[15];
    const float* op; const int* pre_adj; const int* sub_adj; const int* ma_adj;
    const int* bidx;
    float* pre_agg; float* sub_agg; int* counts;
    const float *z_b1, *z_w2, *z_b2, *z_w3, *z_b3;
    float* f1z;
};

__global__ __launch_bounds__(256) void prep_kernel(PrepArgs A)
{
    __shared__ float shmem[544];
    const int blk = blockIdx.x;
    const int t = threadIdx.x;
    if (blk < 960) {
        const PackDesc d = A.d[blk >> 6];
        const int sub = blk & 63;
        const int total = d.kbn * d.nbn * 512;
        const int N = d.nbn * 16;
        for (int idx = sub * 256 + t; idx < total; idx += 64 * 256) {
            const int e = idx & 7;
            const int l = (idx >> 3) & 63;
            const int t2 = idx >> 9;
            const int nb = t2 % d.nbn;
            const int kb = t2 / d.nbn;
            const int k = kb * 32 + ((l >> 4) << 3) + e;
            const int n = nb * 16 + (l & 15);
            const float v = (k < d.kreal) ? d.src[(size_t)k * N + n] : 0.f;
            const ush hi = f2bf(v);
            d.dh[idx] = hi;
            d.dl[idx] = f2bf(v - bf2f(hi));
        }
    } else if (blk < 960 + NROW) {
        const int e = blk - 960;
        const int i = e & 511, b = e >> 9;
        const int bi = A.bidx[b];
        if (t < 64) {
            const int active = (A.ma_adj[((size_t)bi * NOPc + i) * NMAc + t] != 0) ? 1 : 0;
            const unsigned long long mk = __ballot(active);
            if (t == 0) A.counts[(size_t)b * NOPc + i] = (int)__popcll(mk);
        }
        const int d = t & 15, g = t >> 4;
        const int4* pr4 = (const int4*)(A.pre_adj + ((size_t)bi * NOPc + i) * NOPc);
        const int4* sr4 = (const int4*)(A.sub_adj + ((size_t)bi * NOPc + i) * NOPc);
        const float* opb = A.op + (size_t)b * NOPc * 16;
        float ap = 0.f, as = 0.f;
        #pragma unroll 2
        for (int j4 = g; j4 < 128; j4 += 16) {
            const int4 p = pr4[j4];
            const int4 s = sr4[j4];
            const int jb = j4 << 2;
            const float v0 = opb[(jb + 0) * 16 + d];
            const float v1 = opb[(jb + 1) * 16 + d];
            const float v2 = opb[(jb + 2) * 16 + d];
            const float v3 = opb[(jb + 3) * 16 + d];
            if (p.x) ap += v0;  if (p.y) ap += v1;  if (p.z) ap += v2;  if (p.w) ap += v3;
            if (s.x) as += v0;  if (s.y) as += v1;  if (s.z) as += v2;  if (s.w) as += v3;
        }
        shmem[0 * 256 + g * 16 + d] = ap;
        shmem[1 * 256 + g * 16 + d] = as;
        __syncthreads();
        if (t < 32) {
            const int which = t >> 4, dd = t & 15;
            float s = 0.f;
            #pragma unroll
            for (int gg = 0; gg < 16; ++gg) s += shmem[which * 256 + gg * 16 + dd];
            float* dst = which ? A.sub_agg : A.pre_agg;
            dst[((size_t)b * NOPc + i) * 16 + dd] = s;
        }
    } else {
        // f1z = MLP0(0) in raw f32
        shmem[t] = eluf(A.z_b1[t]);
        __syncthreads();
        float acc = A.z_b2[t];
        for (int k = 0; k < 256; ++k) acc += shmem[k] * A.z_w2[(size_t)k * 256 + t];
        __syncthreads();
        shmem[256 + t] = eluf(acc);
        __syncthreads();
        if (t < 128) {
            float a = A.z_b3[t];
            for (int k = 0; k < 256; ++k) a += shmem[256 + k] * A.z_w3[(size_t)k * 128 + t];
            A.f1z[t] = a;
        }
    }
}

// ---------------------------------------------------------------------------
// scan: exclusive prefix over counts[8192] -> bases, natot; zero/sentinel pad.
// ---------------------------------------------------------------------------
__global__ __launch_bounds__(1024) void scan_kernel(const int* __restrict__ counts,
                                                    int* __restrict__ bases,
                                                    int* __restrict__ natot,
                                                    ush* __restrict__ Xq,
                                                    ush* __restrict__ rowseg)
{
    __shared__ int tot[1024];
    const int t = threadIdx.x;
    int loc[8];
    int s = 0;
    #pragma unroll
    for (int k = 0; k < 8; ++k) { loc[k] = s; s += counts[t * 8 + k]; }
    tot[t] = s;
    __syncthreads();
    for (int off = 1; off < 1024; off <<= 1) {
        const int v = (t >= off) ? tot[t - off] : 0;
        __syncthreads();
        tot[t] += v;
        __syncthreads();
    }
    const int base = tot[t] - s;   // exclusive
    #pragma unroll
    for (int k = 0; k < 8; ++k) bases[t * 8 + k] = base + loc[k];
    const int NA = tot[1023];
    if (t == 0) *natot = NA;
    __syncthreads();
    const int NApad = (NA + 63) & ~63;
    for (int idx = NA * 16 + t; idx < NApad * 16; idx += 1024) Xq[idx] = 0;
    for (int idx = NA + t; idx < NApad; idx += 1024) rowseg[idx] = (ush)0xFFFFu;
}

// ---------------------------------------------------------------------------
// scatter: build dense bf16 edge matrix Xq[NA][16] (sorted by rid=(b,i)),
// rowseg[NA]; zero sum.
// ---------------------------------------------------------------------------
__global__ __launch_bounds__(256) void scatter_kernel(
    const float* __restrict__ ma, const float* __restrict__ eg,
    const int* __restrict__ ma_adj, const int* __restrict__ bidx,
    const int* __restrict__ bases,
    ush* __restrict__ Xq, ush* __restrict__ rowseg,
    float* __restrict__ sumG)
{
    const int tid = threadIdx.x;
    const int rid = blockIdx.x * 4 + (tid >> 6);
    const int lane = tid & 63;
    const int b = rid >> 9, i = rid & 511;
    const int bi = bidx[b];
    const int act = (ma_adj[((size_t)bi * NOPc + i) * NMAc + lane] != 0) ? 1 : 0;
    const unsigned long long mk = __ballot(act);
    if (act) {
        const int pos = bases[rid] + (int)__popcll(mk & ((1ull << lane) - 1ull));
        const float4* mp = (const float4*)(ma + ((size_t)b * NMAc + lane) * 8);
        const float4* ep = (const float4*)(eg + (((size_t)b * NOPc + i) * NMAc + lane) * 8);
        const float4 m0 = mp[0], m1 = mp[1], e0 = ep[0], e1 = ep[1];
        uint4 u0, u1;
        u0.x = pkbf_rne(m0.x, m0.y); u0.y = pkbf_rne(m0.z, m0.w);
        u0.z = pkbf_rne(m1.x, m1.y); u0.w = pkbf_rne(m1.z, m1.w);
        u1.x = pkbf_rne(e0.x, e0.y); u1.y = pkbf_rne(e0.z, e0.w);
        u1.z = pkbf_rne(e1.x, e1.y); u1.w = pkbf_rne(e1.z, e1.w);
        uint4* dst = (uint4*)(Xq + (size_t)pos * 16);
        dst[0] = u0;
        dst[1] = u1;
        rowseg[pos] = (ush)rid;
    }
    sumG[(size_t)rid * 128 + lane] = 0.f;
    sumG[(size_t)rid * 128 + 64 + lane] = 0.f;
}

// ---------------------------------------------------------------------------
// Fused kernel: blocks [0,8192) = edge MLP0 tiles; [8192, 8960) = f1 paths
// 0..2 (pre/sub/self), 32 rows each.
// ---------------------------------------------------------------------------
struct EF1Args {
    const ush* Xq; const ush* rowseg; const int* natot; MlpPack P0;
    float* sumG;
    const float* X[3]; MlpPack P[3]; float* f1[3]; float* ut[3];
};

__global__ __launch_bounds__(256, 4) void edge_f1_kernel(EF1Args A, const float* __restrict__ attn)
{
    __shared__ unsigned char smem[36992];
    const int blk = blockIdx.x;
    const int tid = threadIdx.x;
    const int wv = tid >> 6, lane = tid & 63, r = lane & 15, g = lane >> 4;

    if (blk < 8192) {
        // ================= edge path =================
        const int NA = *A.natot;
        const int tile = blk;
        if (tile * 64 >= NA) return;
        ush* Hh = (ush*)smem;                       // 64*256 ush = 32768 B
        ush* segid = (ush*)(smem + 32768);          // 64 ush
        const MlpPack& P = A.P0;
        if (tid < 64) segid[tid] = A.rowseg[(size_t)tile * 64 + tid];

        // ---- layer 1: 32 -> 256, X direct from dense global queue ----
        {
            f32x4 acc[4][4];
            #pragma unroll
            for (int a = 0; a < 4; ++a)
                #pragma unroll
                for (int m = 0; m < 4; ++m) acc[a][m] = f32x4{0.f, 0.f, 0.f, 0.f};
            bf16x8 wh[4];
            #pragma unroll
            for (int a = 0; a < 4; ++a)
                wh[a] = *(const bf16x8*)(P.w1h + ((size_t)(wv * 4 + a) * 64 + lane) * 8);
            #pragma unroll
            for (int m = 0; m < 4; ++m) {
                const int gr = tile * 64 + 16 * m + r;
                bf16x8 xh = {0, 0, 0, 0, 0, 0, 0, 0};
                if (g < 2) xh = *(const bf16x8*)(A.Xq + (size_t)gr * 16 + 8 * g);
                #pragma unroll
                for (int a = 0; a < 4; ++a) acc[a][m] = MFMA(wh[a], xh, acc[a][m]);
            }
            #pragma unroll
            for (int a = 0; a < 4; ++a) {
                const int n0 = (wv * 4 + a) * 16 + 4 * g;
                const float4 bv = *(const float4*)(P.b1 + n0);
                #pragma unroll
                for (int m = 0; m < 4; ++m) {
                    const int row = 16 * m + r;
                    const float y0 = eluf_fast(acc[a][m][0] + bv.x);
                    const float y1 = eluf_fast(acc[a][m][1] + bv.y);
                    const float y2 = eluf_fast(acc[a][m][2] + bv.z);
                    const float y3 = eluf_fast(acc[a][m][3] + bv.w);
                    uint2 u; u.x = pkbf(y0, y1); u.y = pkbf(y2, y3);
                    *(uint2*)(Hh + row * 256 + (n0 ^ (8 * (row & 7)))) = u;
                }
            }
        }
        __syncthreads();

        // ---- layer 2: 256 -> 256 (in place) ----
        {
            f32x4 acc[4][4];
            #pragma unroll
            for (int a = 0; a < 4; ++a)
                #pragma unroll
                for (int m = 0; m < 4; ++m) acc[a][m] = f32x4{0.f, 0.f, 0.f, 0.f};
            #pragma unroll 1
            for (int kb = 0; kb < 8; ++kb) {
                bf16x8 wh[4];
                #pragma unroll
                for (int a = 0; a < 4; ++a)
                    wh[a] = *(const bf16x8*)(P.w2h + ((size_t)(kb * 16 + (wv * 4 + a)) * 64 + lane) * 8);
                #pragma unroll
                for (int m = 0; m < 4; ++m) {
                    const int row = 16 * m + r;
                    const int k0 = kb * 32 + 8 * g;
                    bf16x8 hh = *(const bf16x8*)(Hh + row * 256 + (k0 ^ (8 * (row & 7))));
                    #pragma unroll
                    for (int a = 0; a < 4; ++a) acc[a][m] = MFMA(wh[a], hh, acc[a][m]);
                }
            }
            __syncthreads();
            #pragma unroll
            for (int a = 0; a < 4; ++a) {
                const int n0 = (wv * 4 + a) * 16 + 4 * g;
                const float4 bv = *(const float4*)(P.b2 + n0);
                #pragma unroll
                for (int m = 0; m < 4; ++m) {
                    const int row = 16 * m + r;
                    const float y0 = eluf_fast(acc[a][m][0] + bv.x);
                    const float y1 = eluf_fast(acc[a][m][1] + bv.y);
                    const float y2 = eluf_fast(acc[a][m][2] + bv.z);
                    const float y3 = eluf_fast(acc[a][m][3] + bv.w);
                    uint2 u; u.x = pkbf(y0, y1); u.y = pkbf(y2, y3);
                    *(uint2*)(Hh + row * 256 + (n0 ^ (8 * (row & 7)))) = u;
                }
            }
        }
        __syncthreads();

        // ---- layer 3: 256 -> 128 ----
        f32x4 acc3[2][4];
        #pragma unroll
        for (int a = 0; a < 2; ++a)
            #pragma unroll
            for (int m = 0; m < 4; ++m) acc3[a][m] = f32x4{0.f, 0.f, 0.f, 0.f};
        #pragma unroll 1
        for (int kb = 0; kb < 8; ++kb) {
            bf16x8 wh[2];
            #pragma unroll
            for (int a = 0; a < 2; ++a)
                wh[a] = *(const bf16x8*)(P.w3h + ((size_t)(kb * 8 + (wv * 2 + a)) * 64 + lane) * 8);
            #pragma unroll
            for (int m = 0; m < 4; ++m) {
                const int row = 16 * m + r;
                const int k0 = kb * 32 + 8 * g;
                bf16x8 hh = *(const bf16x8*)(Hh + row * 256 + (k0 ^ (8 * (row & 7))));
                #pragma unroll
                for (int a = 0; a < 2; ++a) acc3[a][m] = MFMA(wh[a], hh, acc3[a][m]);
            }
        }
        __syncthreads();            // all Hh reads complete before aliasing as f1buf

        // ---- write y rows to LDS f1buf (f32, XOR-swizzled) ----
        float* f1buf = (float*)Hh;
        #pragma unroll
        for (int a = 0; a < 2; ++a) {
            const int n0 = (wv * 2 + a) * 16 + 4 * g;
            const float4 bv = *(const float4*)(P.b3 + n0);
            #pragma unroll
            for (int m = 0; m < 4; ++m) {
                const int row = 16 * m + r;
                float4 y;
                y.x = acc3[a][m][0] + bv.x;
                y.y = acc3[a][m][1] + bv.y;
                y.z = acc3[a][m][2] + bv.z;
                y.w = acc3[a][m][3] + bv.w;
                *(float4*)&f1buf[row * 128 + (n0 ^ ((row & 7) << 2))] = y;
            }
        }
        __syncthreads();

        // ---- segmented SUM pooling (cnt analytic): thread = 4 cols x 8 rows.
        //      XOR swizzle preserves aligned-4 col contiguity -> float4 reads.
        {
            const int c4 = 4 * (tid & 31);
            const int r0p = (tid >> 5) * 8;        // rows r0p..r0p+7; (r0p+j)&7 == j
            float4 accS = {0.f, 0.f, 0.f, 0.f};
            int cur = -1;
            #pragma unroll
            for (int j = 0; j < 8; ++j) {
                const int rl = r0p + j;
                const int sg = (int)segid[rl];
                if (sg != cur) {
                    if ((unsigned)cur < (unsigned)NROW) {
                        float* dst = &A.sumG[(size_t)cur * 128 + c4];
                        atomicAdd(dst + 0, accS.x);
                        atomicAdd(dst + 1, accS.y);
                        atomicAdd(dst + 2, accS.z);
                        atomicAdd(dst + 3, accS.w);
                    }
                    cur = sg; accS = {0.f, 0.f, 0.f, 0.f};
                }
                const float4 y = *(const float4*)&f1buf[rl * 128 + (c4 ^ (j << 2))];
                accS.x += y.x; accS.y += y.y; accS.z += y.z; accS.w += y.w;
            }
            if ((unsigned)cur < (unsigned)NROW) {
                float* dst = &A.sumG[(size_t)cur * 128 + c4];
                atomicAdd(dst + 0, accS.x);
                atomicAdd(dst + 1, accS.y);
                atomicAdd(dst + 2, accS.z);
                atomicAdd(dst + 3, accS.w);
            }
        }
    } else {
        // ================= f1 paths 0..2 (32-row tiles) =================
        const int pb = blk - 8192;
        const int p = pb >> 8;
        const int row0 = (pb & 255) * 32;
        ush* Xh = (ush*)smem;                        // 32*32 = 2048 B
        ush* Xl = (ush*)(smem + 2048);
        ush* Hh = (ush*)(smem + 4096);               // 32*256 = 16384 B
        ush* Hl = (ush*)(smem + 20480);
        float* UT = (float*)(smem + 36864);          // 32 floats
        const float* Xg = A.X[p];
        const MlpPack P = A.P[p];
        float* f1_out = A.f1[p];
        float* ut_out = A.ut[p];
        if (tid < 32) UT[tid] = 0.f;
        for (int idx = tid; idx < 32 * 32; idx += 256) {
            const int row = idx >> 5, k = idx & 31;
            float v = 0.f;
            if (k < 16) v = Xg[(size_t)(row0 + row) * 16 + k];
            const uint32 uv = __float_as_uint(v);
            Xh[idx] = (ush)(uv >> 16);
            const float rest = v - __uint_as_float(uv & 0xFFFF0000u);
            Xl[idx] = (ush)(__float_as_uint(rest) >> 16);
        }
        __syncthreads();
        f32x4 acc3[2][2];
        mlp3_core32(P, 1, Xh, Xl, Hh, Hl, acc3);

        float utp[2] = {0.f, 0.f};
        #pragma unroll
        for (int a = 0; a < 2; ++a) {
            const int n0 = (wv * 2 + a) * 16 + 4 * g;
            const float4 bv = *(const float4*)(P.b3 + n0);
            const float4 av = *(const float4*)(attn + n0);
            #pragma unroll
            for (int m = 0; m < 2; ++m) {
                float4 y;
                y.x = acc3[a][m][0] + bv.x;
                y.y = acc3[a][m][1] + bv.y;
                y.z = acc3[a][m][2] + bv.z;
                y.w = acc3[a][m][3] + bv.w;
                *(float4*)&f1_out[(size_t)(row0 + 16 * m + r) * OUTc + n0] = y;
                utp[m] += y.x * av.x + y.y * av.y + y.z * av.z + y.w * av.w;
            }
        }
        #pragma unroll
        for (int m = 0; m < 2; ++m) {
            float v = utp[m];
            v += __shfl_xor(v, 16);
            v += __shfl_xor(v, 32);
            if (lane < 16) atomicAdd(&UT[16 * m + r], v);
        }
        __syncthreads();
        if (tid < 32) ut_out[row0 + tid] = UT[tid];
    }
}

// ---------------------------------------------------------------------------
// MLP4 path (depends on edge results): 32 rows/block, finalizes x2 inline.
// cnt is analytic: active rows each contribute 1; inactive contribute [f1z!=0].
// ---------------------------------------------------------------------------
__global__ __launch_bounds__(256, 3) void p3_kernel(
    MlpPack P, const float* __restrict__ attn,
    const float* __restrict__ sumG,
    const int* __restrict__ counts, const float* __restrict__ f1z,
    float* __restrict__ f1_out, float* __restrict__ ut_out)
{
    __shared__ ush Xh[32 * 128], Xl[32 * 128];
    __shared__ ush Hh[32 * 256], Hl[32 * 256];
    __shared__ float UT[32];
    const int tid = threadIdx.x;
    const int row0 = blockIdx.x * 32;
    if (tid < 32) UT[tid] = 0.f;
    for (int idx = tid; idx < 32 * 128; idx += 256) {
        const int row = idx >> 7, k = idx & 127;
        const size_t rid = (size_t)(row0 + row);
        const float na = (float)counts[rid];
        const float nz = 64.f - na;
        const float fz = f1z[k];
        const float v = (sumG[rid * 128 + k] + nz * fz)
                      / (na + nz * ((fz != 0.f) ? 1.f : 0.f));
        const uint32 uv = __float_as_uint(v);
        Xh[idx] = (ush)(uv >> 16);
        const float rest = v - __uint_as_float(uv & 0xFFFF0000u);
        Xl[idx] = (ush)(__float_as_uint(rest) >> 16);
    }
    __syncthreads();
    f32x4 acc3[2][2];
    mlp3_core32(P, 4, Xh, Xl, Hh, Hl, acc3);

    const int wv = tid >> 6, lane = tid & 63, r = lane & 15, g = lane >> 4;
    float utp[2] = {0.f, 0.f};
    #pragma unroll
    for (int a = 0; a < 2; ++a) {
        const int n0 = (wv * 2 + a) * 16 + 4 * g;
        const float4 bv = *(const float4*)(P.b3 + n0);
        const float4 av = *(const float4*)(attn + n0);
        #pragma unroll
        for (int m = 0; m < 2; ++m) {
            float4 y;
            y.x = acc3[a][m][0] + bv.x;
            y.y = acc3[a][m][1] + bv.y;
            y.z = acc3[a][m][2] + bv.z;
            y.w = acc3[a][m][3] + bv.w;
            *(float4*)&f1_out[(size_t)(row0 + 16 * m + r) * OUTc + n0] = y;
            utp[m] += y.x * av.x + y.y * av.y + y.z * av.z + y.w * av.w;
        }
    }
    #pragma unroll
    for (int m = 0; m < 2; ++m) {
        float v = utp[m];
        v += __shfl_xor(v, 16);
        v += __shfl_xor(v, 32);
        if (lane < 16) atomicAdd(&UT[16 * m + r], v);
    }
    __syncthreads();
    if (tid < 32) ut_out[row0 + tid] = UT[tid];
}

// ---------------------------------------------------------------------------
// combine with inline per-batch softmax: block = (b, 32-row chunk).
// ---------------------------------------------------------------------------
__global__ __launch_bounds__(256) void combine2_kernel(
    const float* __restrict__ uts,
    const float* __restrict__ pre_f1, const float* __restrict__ sub_f1,
    const float* __restrict__ self_f1, const float* __restrict__ ma_f2,
    float* __restrict__ out)
{
    __shared__ float sc[4 * NOPc];
    __shared__ float red[256];
    const int b = blockIdx.x >> 4, chunk = blockIdx.x & 15;
    const int t = threadIdx.x;
    const float* put = uts + 0 * NROW + (size_t)b * NOPc;
    const float* sut = uts + 1 * NROW + (size_t)b * NOPc;
    const float* eut = uts + 2 * NROW + (size_t)b * NOPc;
    const float* mut = uts + 3 * NROW + (size_t)b * NOPc;
    for (int i = t; i < NOPc; i += 256) {
        const float se = eut[i];
        const float s0 = put[i] + se, s1 = sut[i] + se, s2 = se + se, s3 = mut[i] + se;
        sc[0 * NOPc + i] = s0 > 0.f ? s0 : 0.2f * s0;
        sc[1 * NOPc + i] = s1 > 0.f ? s1 : 0.2f * s1;
        sc[2 * NOPc + i] = s2 > 0.f ? s2 : 0.2f * s2;
        sc[3 * NOPc + i] = s3 > 0.f ? s3 : 0.2f * s3;
    }
    __syncthreads();
    float mx = -INFINITY;
    for (int idx = t; idx < 4 * NOPc; idx += 256) mx = fmaxf(mx, sc[idx]);
    red[t] = mx;
    __syncthreads();
    for (int s = 128; s > 0; s >>= 1) { if (t < s) red[t] = fmaxf(red[t], red[t + s]); __syncthreads(); }
    mx = red[0];
    __syncthreads();
    float ps = 0.f;
    for (int idx = t; idx < 4 * NOPc; idx += 256) {
        const float e = expf(sc[idx] - mx);
        sc[idx] = e;
        ps += e;
    }
    red[t] = ps;
    __syncthreads();
    for (int s = 128; s > 0; s >>= 1) { if (t < s) red[t] += red[t + s]; __syncthreads(); }
    const float invZ = 1.f / red[0];

    const size_t base4 = (size_t)b * 16384 + (size_t)chunk * 1024;   // float4 units
    #pragma unroll
    for (int k = 0; k < 4; ++k) {
        const size_t e4 = base4 + k * 256 + t;
        const int i = (int)((e4 >> 5) & 511);
        const float a0 = sc[0 * NOPc + i] * invZ;
        const float a1 = sc[1 * NOPc + i] * invZ;
        const float a2 = sc[2 * NOPc + i] * invZ;
        const float a3 = sc[3 * NOPc + i] * invZ;
        const float4 vp = ((const float4*)pre_f1)[e4];
        const float4 vs = ((const float4*)sub_f1)[e4];
        const float4 ve = ((const float4*)self_f1)[e4];
        const float4 vm = ((const float4*)ma_f2)[e4];
        float4 o;
        o.x = 1.f / (1.f + expf(-(a0 * vp.x + a1 * vs.x + a2 * ve.x + a3 * vm.x)));
        o.y = 1.f / (1.f + expf(-(a0 * vp.y + a1 * vs.y + a2 * ve.y + a3 * vm.y)));
        o.z = 1.f / (1.f + expf(-(a0 * vp.z + a1 * vs.z + a2 * ve.z + a3 * vm.z)));
        o.w = 1.f / (1.f + expf(-(a0 * vp.w + a1 * vs.w + a2 * ve.w + a3 * vm.w)));
        ((float4*)out)[e4] = o;
    }
}

extern "C" void kernel_launch(void* const* d_in, const int* in_sizes, int n_in,
                              void* d_out, int out_size, void* d_ws, size_t ws_size,
                              hipStream_t stream) {
    const float* op      = (const float*)d_in[0];
    const float* ma      = (const float*)d_in[1];
    const float* eg      = (const float*)d_in[2];
    const int*   ma_adj  = (const int*)d_in[3];
    const int*   pre_adj = (const int*)d_in[4];
    const int*   sub_adj = (const int*)d_in[5];
    const int*   bidx    = (const int*)d_in[6];
    const float* attn    = (const float*)d_in[7];
    float* out = (float*)d_out;
    const float* Wraw[5][6];
    for (int m = 0; m < 5; ++m)
        for (int j = 0; j < 6; ++j)
            Wraw[m][j] = (const float*)d_in[8 + 6 * m + j];

    // ---- workspace layout ----
    float* wsf = (float*)d_ws;
    float* pre_agg = wsf;  wsf += (size_t)NROW * 16;
    float* sub_agg = wsf;  wsf += (size_t)NROW * 16;
    float* pre_f1  = wsf;  wsf += (size_t)NROW * OUTc;
    float* sub_f1  = wsf;  wsf += (size_t)NROW * OUTc;
    float* self_f1 = wsf;  wsf += (size_t)NROW * OUTc;
    float* ma_f2   = wsf;  wsf += (size_t)NROW * OUTc;
    float* uts     = wsf;  wsf += (size_t)4 * NROW;
    float* f1z     = wsf;  wsf += 128;
    float* sumG    = wsf;  wsf += (size_t)NROW * 128;
    int*   counts  = (int*)wsf;   wsf += NROW;
    int*   bases   = (int*)wsf;   wsf += NROW;
    int*   natot   = (int*)wsf;   wsf += 16;
    ush*   rowseg  = (ush*)wsf;   wsf += NEMAX / 2;
    ush*   Xq      = (ush*)wsf;   wsf += (size_t)NEMAX * 8;   // NEMAX rows * 16 ush
    ush*   packp   = (ush*)wsf;

    PrepArgs pa;
    MlpPack pk[5];
    for (int m = 0; m < 5; ++m) {
        const int kre[3] = { (m == 4 ? 128 : 16), 256, 256 };
        const int kbn[3] = { (m == 4 ? 4 : 1), 8, 8 };
        const int nbn[3] = { 16, 16, 8 };
        const ush* dh[3]; const ush* dl[3];
        for (int j = 0; j < 3; ++j) {
            const int id = m * 3 + j;
            pa.d[id].src = Wraw[m][2 * j];
            pa.d[id].kreal = kre[j];
            pa.d[id].kbn = kbn[j];
            pa.d[id].nbn = nbn[j];
            const int cnt = kbn[j] * nbn[j] * 512;
            pa.d[id].dh = packp; dh[j] = packp; packp += cnt;
            pa.d[id].dl = packp; dl[j] = packp; packp += cnt;
        }
        pk[m].w1h = dh[0]; pk[m].w1l = dl[0];
        pk[m].w2h = dh[1]; pk[m].w2l = dl[1];
        pk[m].w3h = dh[2]; pk[m].w3l = dl[2];
        pk[m].b1 = Wraw[m][1]; pk[m].b2 = Wraw[m][3]; pk[m].b3 = Wraw[m][5];
    }
    pa.op = op; pa.pre_adj = pre_adj; pa.sub_adj = sub_adj; pa.ma_adj = ma_adj;
    pa.bidx = bidx;
    pa.pre_agg = pre_agg; pa.sub_agg = sub_agg; pa.counts = counts;
    pa.z_b1 = Wraw[0][1]; pa.z_w2 = Wraw[0][2]; pa.z_b2 = Wraw[0][3];
    pa.z_w3 = Wraw[0][4]; pa.z_b3 = Wraw[0][5];
    pa.f1z = f1z;

    EF1Args ea;
    ea.Xq = Xq; ea.rowseg = rowseg; ea.natot = natot; ea.P0 = pk[0];
    ea.sumG = sumG;
    ea.X[0] = pre_agg; ea.X[1] = sub_agg; ea.X[2] = op;
    ea.P[0] = pk[1];   ea.P[1] = pk[2];   ea.P[2] = pk[3];
    ea.f1[0] = pre_f1; ea.f1[1] = sub_f1; ea.f1[2] = self_f1;
    ea.ut[0] = uts + 0 * NROW;
    ea.ut[1] = uts + 1 * NROW;
    ea.ut[2] = uts + 2 * NROW;

    prep_kernel<<<dim3(960 + NROW + 1), 256, 0, stream>>>(pa);
    scan_kernel<<<1, 1024, 0, stream>>>(counts, bases, natot, Xq, rowseg);
    scatter_kernel<<<dim3(NROW / 4), 256, 0, stream>>>(ma, eg, ma_adj, bidx, bases,
                                                       Xq, rowseg, sumG);
    edge_f1_kernel<<<dim3(8192 + 768), 256, 0, stream>>>(ea, attn);
    p3_kernel<<<dim3(256), 256, 0, stream>>>(pk[4], attn, sumG, counts, f1z,
                                             ma_f2, uts + 3 * NROW);
    combine2_kernel<<<dim3(NBb * 16), 256, 0, stream>>>(uts, pre_f1, sub_f1, self_f1, ma_f2, out);
}

// Round 11
// 164.957 us; speedup vs baseline: 1.1473x; 1.1473x over previous
//
#include <hip/hip_runtime.h>
#include <math.h>

#define NBb  16
#define NOPc 512
#define NMAc 64
#define HIDc 256
#define OUTc 128
#define NROW (NBb * NOPc)          // 8192 (b,i) rows
#define NEMAX (NROW * NMAc)        // 524288 max edges

// LDS swizzles: row stride of H is 512B (bank-aligned), so fold 4 row bits
// into the column. Bits 3-6 (ush) / 2-5 (f32) stay above vector low bits.
#define HX(row, col) ((col) ^ (8 * ((row) & 15)))    // ush units (H buffers)
#define FX(row, col) ((col) ^ (4 * ((row) & 15)))    // f32 units (f1buf)

typedef unsigned int uint32;
typedef unsigned short ush;
typedef __attribute__((ext_vector_type(8))) short bf16x8;
typedef __attribute__((ext_vector_type(4))) float f32x4;

__device__ __forceinline__ ush f2bf(float v) {
    uint32 u = __float_as_uint(v);
    u += 0x7FFFu + ((u >> 16) & 1u);
    return (ush)(u >> 16);
}
__device__ __forceinline__ float bf2f(ush b) { return __uint_as_float(((uint32)b) << 16); }
__device__ __forceinline__ float eluf(float x) { return x > 0.f ? x : expm1f(x); }
__device__ __forceinline__ float eluf_fast(float x) { return x > 0.f ? x : __expf(x) - 1.f; }
// pack two floats' truncated bf16 into one u32: low = bf16(a), high = bf16(b)
__device__ __forceinline__ uint32 pkbf(float a, float b) {
    return __builtin_amdgcn_perm(__float_as_uint(b), __float_as_uint(a), 0x07060302u);
}
__device__ __forceinline__ uint32 pkbf_rne(float a, float b) {
    return (uint32)f2bf(a) | ((uint32)f2bf(b) << 16);
}
// truncation hi/lo split of 2 floats (residual captured exactly by lo plane)
__device__ __forceinline__ void split2(float a, float b, uint32& hp, uint32& lp) {
    const uint32 ua = __float_as_uint(a), ub = __float_as_uint(b);
    hp = __builtin_amdgcn_perm(ub, ua, 0x07060302u);
    const float ra = a - __uint_as_float(ua & 0xFFFF0000u);
    const float rb = b - __uint_as_float(ub & 0xFFFF0000u);
    lp = __builtin_amdgcn_perm(__float_as_uint(rb), __float_as_uint(ra), 0x07060302u);
}

#define MFMA(A, B, C) __builtin_amdgcn_mfma_f32_16x16x32_bf16((A), (B), (C), 0, 0, 0)

// pack[((kb*nbn + nb)*64 + lane)*8 + e] = W[kb*32 + 8*(lane>>4) + e][nb*16 + (lane&15)]
struct MlpPack {
    const ush *w1h, *w1l, *w2h, *w2l, *w3h, *w3l;
    const float *b1, *b2, *b3;
};

// ---------------------------------------------------------------------------
// Hi/lo (bf16x3) 3-layer core over a 32-row tile (pre/sub/self/MLP4 paths).
// ---------------------------------------------------------------------------
__device__ __forceinline__ void mlp3_core32(
    const MlpPack& P, const int KB1,
    const ush* Xh, const ush* Xl, ush* Hh, ush* Hl, f32x4 acc3[2][2])
{
    const int tid = threadIdx.x;
    const int wv = tid >> 6, lane = tid & 63, r = lane & 15, g = lane >> 4;
    const int KX = KB1 * 32;

    // layer 1: KX -> 256
    {
        f32x4 acc[4][2];
        #pragma unroll
        for (int a = 0; a < 4; ++a)
            #pragma unroll
            for (int m = 0; m < 2; ++m) acc[a][m] = f32x4{0.f, 0.f, 0.f, 0.f};
        #pragma unroll 1
        for (int kb = 0; kb < KB1; ++kb) {
            bf16x8 wh[4], wl[4];
            #pragma unroll
            for (int a = 0; a < 4; ++a) {
                const size_t o = ((size_t)(kb * 16 + (wv * 4 + a)) * 64 + lane) * 8;
                wh[a] = *(const bf16x8*)(P.w1h + o);
                wl[a] = *(const bf16x8*)(P.w1l + o);
            }
            #pragma unroll
            for (int m = 0; m < 2; ++m) {
                const int row = 16 * m + r;
                const int ki = kb * 32 + 8 * g;
                bf16x8 xh = *(const bf16x8*)(Xh + row * KX + ki);
                bf16x8 xl = *(const bf16x8*)(Xl + row * KX + ki);
                #pragma unroll
                for (int a = 0; a < 4; ++a) {
                    acc[a][m] = MFMA(wh[a], xh, acc[a][m]);
                    acc[a][m] = MFMA(wh[a], xl, acc[a][m]);
                    acc[a][m] = MFMA(wl[a], xh, acc[a][m]);
                }
            }
        }
        #pragma unroll
        for (int a = 0; a < 4; ++a) {
            const int n0 = (wv * 4 + a) * 16 + 4 * g;
            const float4 bv = *(const float4*)(P.b1 + n0);
            #pragma unroll
            for (int m = 0; m < 2; ++m) {
                const int row = 16 * m + r;
                const float y0 = eluf_fast(acc[a][m][0] + bv.x);
                const float y1 = eluf_fast(acc[a][m][1] + bv.y);
                const float y2 = eluf_fast(acc[a][m][2] + bv.z);
                const float y3 = eluf_fast(acc[a][m][3] + bv.w);
                uint2 uh, ul;
                split2(y0, y1, uh.x, ul.x);
                split2(y2, y3, uh.y, ul.y);
                const int idx = row * 256 + HX(row, n0);
                *(uint2*)(Hh + idx) = uh;
                *(uint2*)(Hl + idx) = ul;
            }
        }
    }
    __syncthreads();

    // layer 2: 256 -> 256 (in place)
    {
        f32x4 acc[4][2];
        #pragma unroll
        for (int a = 0; a < 4; ++a)
            #pragma unroll
            for (int m = 0; m < 2; ++m) acc[a][m] = f32x4{0.f, 0.f, 0.f, 0.f};
        #pragma unroll 1
        for (int kb = 0; kb < 8; ++kb) {
            bf16x8 wh[4], wl[4];
            #pragma unroll
            for (int a = 0; a < 4; ++a) {
                const size_t o = ((size_t)(kb * 16 + (wv * 4 + a)) * 64 + lane) * 8;
                wh[a] = *(const bf16x8*)(P.w2h + o);
                wl[a] = *(const bf16x8*)(P.w2l + o);
            }
            #pragma unroll
            for (int m = 0; m < 2; ++m) {
                const int row = 16 * m + r;
                const int k0 = kb * 32 + 8 * g;
                const int idx = row * 256 + HX(row, k0);
                bf16x8 hh = *(const bf16x8*)(Hh + idx);
                bf16x8 hl = *(const bf16x8*)(Hl + idx);
                #pragma unroll
                for (int a = 0; a < 4; ++a) {
                    acc[a][m] = MFMA(wh[a], hh, acc[a][m]);
                    acc[a][m] = MFMA(wh[a], hl, acc[a][m]);
                    acc[a][m] = MFMA(wl[a], hh, acc[a][m]);
                }
            }
        }
        __syncthreads();
        #pragma unroll
        for (int a = 0; a < 4; ++a) {
            const int n0 = (wv * 4 + a) * 16 + 4 * g;
            const float4 bv = *(const float4*)(P.b2 + n0);
            #pragma unroll
            for (int m = 0; m < 2; ++m) {
                const int row = 16 * m + r;
                const float y0 = eluf_fast(acc[a][m][0] + bv.x);
                const float y1 = eluf_fast(acc[a][m][1] + bv.y);
                const float y2 = eluf_fast(acc[a][m][2] + bv.z);
                const float y3 = eluf_fast(acc[a][m][3] + bv.w);
                uint2 uh, ul;
                split2(y0, y1, uh.x, ul.x);
                split2(y2, y3, uh.y, ul.y);
                const int idx = row * 256 + HX(row, n0);
                *(uint2*)(Hh + idx) = uh;
                *(uint2*)(Hl + idx) = ul;
            }
        }
    }
    __syncthreads();

    // layer 3: 256 -> 128
    {
        #pragma unroll
        for (int a = 0; a < 2; ++a)
            #pragma unroll
            for (int m = 0; m < 2; ++m) acc3[a][m] = f32x4{0.f, 0.f, 0.f, 0.f};
        #pragma unroll 1
        for (int kb = 0; kb < 8; ++kb) {
            bf16x8 wh[2], wl[2];
            #pragma unroll
            for (int a = 0; a < 2; ++a) {
                const size_t o = ((size_t)(kb * 8 + (wv * 2 + a)) * 64 + lane) * 8;
                wh[a] = *(const bf16x8*)(P.w3h + o);
                wl[a] = *(const bf16x8*)(P.w3l + o);
            }
            #pragma unroll
            for (int m = 0; m < 2; ++m) {
                const int row = 16 * m + r;
                const int k0 = kb * 32 + 8 * g;
                const int idx = row * 256 + HX(row, k0);
                bf16x8 hh = *(const bf16x8*)(Hh + idx);
                bf16x8 hl = *(const bf16x8*)(Hl + idx);
                #pragma unroll
                for (int a = 0; a < 2; ++a) {
                    acc3[a][m] = MFMA(wh[a], hh, acc3[a][m]);
                    acc3[a][m] = MFMA(wh[a], hl, acc3[a][m]);
                    acc3[a][m] = MFMA(wl[a], hh, acc3[a][m]);
                }
            }
        }
    }
}

// ---------------------------------------------------------------------------
// prep: pack (blocks [0,960)) + agg/ma-count ([960,9152)) + f1z (last).
// ---------------------------------------------------------------------------
struct PackDesc { const float* src; ush* dh; ush* dl; int kreal; int kbn; int nbn; };
struct PrepArgs {
    PackDesc d[15];
    const float* op; const int* pre_adj; const int* sub_adj; const int* ma_adj;
    const int* bidx;
    float* pre_agg; float* sub_agg; int* counts;
    const float *z_b1, *z_w2, *z_b2, *z_w3, *z_b3;
    float* f1z;
};

__global__ __launch_bounds__(256) void prep_kernel(PrepArgs A)
{
    __shared__ float shmem[544];
    const int blk = blockIdx.x;
    const int t = threadIdx.x;
    if (blk < 960) {
        const PackDesc d = A.d[blk >> 6];
        const int sub = blk & 63;
        const int total = d.kbn * d.nbn * 512;
        const int N = d.nbn * 16;
        for (int idx = sub * 256 + t; idx < total; idx += 64 * 256) {
            const int e = idx & 7;
            const int l = (idx >> 3) & 63;
            const int t2 = idx >> 9;
            const int nb = t2 % d.nbn;
            const int kb = t2 / d.nbn;
            const int k = kb * 32 + ((l >> 4) << 3) + e;
            const int n = nb * 16 + (l & 15);
            const float v = (k < d.kreal) ? d.src[(size_t)k * N + n] : 0.f;
            const ush hi = f2bf(v);
            d.dh[idx] = hi;
            d.dl[idx] = f2bf(v - bf2f(hi));
        }
    } else if (blk < 960 + NROW) {
        const int e = blk - 960;
        const int i = e & 511, b = e >> 9;
        const int bi = A.bidx[b];
        if (t < 64) {
            const int active = (A.ma_adj[((size_t)bi * NOPc + i) * NMAc + t] != 0) ? 1 : 0;
            const unsigned long long mk = __ballot(active);
            if (t == 0) A.counts[(size_t)b * NOPc + i] = (int)__popcll(mk);
        }
        const int d = t & 15, g = t >> 4;
        const int4* pr4 = (const int4*)(A.pre_adj + ((size_t)bi * NOPc + i) * NOPc);
        const int4* sr4 = (const int4*)(A.sub_adj + ((size_t)bi * NOPc + i) * NOPc);
        const float* opb = A.op + (size_t)b * NOPc * 16;
        float ap = 0.f, as = 0.f;
        #pragma unroll 2
        for (int j4 = g; j4 < 128; j4 += 16) {
            const int4 p = pr4[j4];
            const int4 s = sr4[j4];
            const int jb = j4 << 2;
            const float v0 = opb[(jb + 0) * 16 + d];
            const float v1 = opb[(jb + 1) * 16 + d];
            const float v2 = opb[(jb + 2) * 16 + d];
            const float v3 = opb[(jb + 3) * 16 + d];
            if (p.x) ap += v0;  if (p.y) ap += v1;  if (p.z) ap += v2;  if (p.w) ap += v3;
            if (s.x) as += v0;  if (s.y) as += v1;  if (s.z) as += v2;  if (s.w) as += v3;
        }
        shmem[0 * 256 + g * 16 + d] = ap;
        shmem[1 * 256 + g * 16 + d] = as;
        __syncthreads();
        if (t < 32) {
            const int which = t >> 4, dd = t & 15;
            float s = 0.f;
            #pragma unroll
            for (int gg = 0; gg < 16; ++gg) s += shmem[which * 256 + gg * 16 + dd];
            float* dst = which ? A.sub_agg : A.pre_agg;
            dst[((size_t)b * NOPc + i) * 16 + dd] = s;
        }
    } else {
        // f1z = MLP0(0) in raw f32
        shmem[t] = eluf(A.z_b1[t]);
        __syncthreads();
        float acc = A.z_b2[t];
        for (int k = 0; k < 256; ++k) acc += shmem[k] * A.z_w2[(size_t)k * 256 + t];
        __syncthreads();
        shmem[256 + t] = eluf(acc);
        __syncthreads();
        if (t < 128) {
            float a = A.z_b3[t];
            for (int k = 0; k < 256; ++k) a += shmem[256 + k] * A.z_w3[(size_t)k * 128 + t];
            A.f1z[t] = a;
        }
    }
}

// ---------------------------------------------------------------------------
// scan: exclusive prefix over counts[8192] -> bases, natot; zero/sentinel pad.
// ---------------------------------------------------------------------------
__global__ __launch_bounds__(1024) void scan_kernel(const int* __restrict__ counts,
                                                    int* __restrict__ bases,
                                                    int* __restrict__ natot,
                                                    ush* __restrict__ Xq,
                                                    ush* __restrict__ rowseg)
{
    __shared__ int tot[1024];
    const int t = threadIdx.x;
    int loc[8];
    int s = 0;
    #pragma unroll
    for (int k = 0; k < 8; ++k) { loc[k] = s; s += counts[t * 8 + k]; }
    tot[t] = s;
    __syncthreads();
    for (int off = 1; off < 1024; off <<= 1) {
        const int v = (t >= off) ? tot[t - off] : 0;
        __syncthreads();
        tot[t] += v;
        __syncthreads();
    }
    const int base = tot[t] - s;   // exclusive
    #pragma unroll
    for (int k = 0; k < 8; ++k) bases[t * 8 + k] = base + loc[k];
    const int NA = tot[1023];
    if (t == 0) *natot = NA;
    __syncthreads();
    const int NApad = (NA + 63) & ~63;
    for (int idx = NA * 16 + t; idx < NApad * 16; idx += 1024) Xq[idx] = 0;
    for (int idx = NA + t; idx < NApad; idx += 1024) rowseg[idx] = (ush)0xFFFFu;
}

// ---------------------------------------------------------------------------
// scatter: build dense bf16 edge matrix Xq[NA][16] (sorted by rid=(b,i)),
// rowseg[NA]; zero sum.
// ---------------------------------------------------------------------------
__global__ __launch_bounds__(256) void scatter_kernel(
    const float* __restrict__ ma, const float* __restrict__ eg,
    const int* __restrict__ ma_adj, const int* __restrict__ bidx,
    const int* __restrict__ bases,
    ush* __restrict__ Xq, ush* __restrict__ rowseg,
    float* __restrict__ sumG)
{
    const int tid = threadIdx.x;
    const int rid = blockIdx.x * 4 + (tid >> 6);
    const int lane = tid & 63;
    const int b = rid >> 9, i = rid & 511;
    const int bi = bidx[b];
    const int act = (ma_adj[((size_t)bi * NOPc + i) * NMAc + lane] != 0) ? 1 : 0;
    const unsigned long long mk = __ballot(act);
    if (act) {
        const int pos = bases[rid] + (int)__popcll(mk & ((1ull << lane) - 1ull));
        const float4* mp = (const float4*)(ma + ((size_t)b * NMAc + lane) * 8);
        const float4* ep = (const float4*)(eg + (((size_t)b * NOPc + i) * NMAc + lane) * 8);
        const float4 m0 = mp[0], m1 = mp[1], e0 = ep[0], e1 = ep[1];
        uint4 u0, u1;
        u0.x = pkbf_rne(m0.x, m0.y); u0.y = pkbf_rne(m0.z, m0.w);
        u0.z = pkbf_rne(m1.x, m1.y); u0.w = pkbf_rne(m1.z, m1.w);
        u1.x = pkbf_rne(e0.x, e0.y); u1.y = pkbf_rne(e0.z, e0.w);
        u1.z = pkbf_rne(e1.x, e1.y); u1.w = pkbf_rne(e1.z, e1.w);
        uint4* dst = (uint4*)(Xq + (size_t)pos * 16);
        dst[0] = u0;
        dst[1] = u1;
        rowseg[pos] = (ush)rid;
    }
    sumG[(size_t)rid * 128 + lane] = 0.f;
    sumG[(size_t)rid * 128 + 64 + lane] = 0.f;
}

// ---------------------------------------------------------------------------
// Fused kernel: blocks [0,8192) = edge MLP0 tiles; [8192, 8960) = f1 paths
// 0..2 (pre/sub/self), 32 rows each.
// ---------------------------------------------------------------------------
struct EF1Args {
    const ush* Xq; const ush* rowseg; const int* natot; MlpPack P0;
    float* sumG;
    const float* X[3]; MlpPack P[3]; float* f1[3]; float* ut[3];
};

__global__ __launch_bounds__(256, 4) void edge_f1_kernel(EF1Args A, const float* __restrict__ attn)
{
    __shared__ unsigned char smem[36992];
    const int blk = blockIdx.x;
    const int tid = threadIdx.x;
    const int wv = tid >> 6, lane = tid & 63, r = lane & 15, g = lane >> 4;

    if (blk < 8192) {
        // ================= edge path =================
        const int NA = *A.natot;
        const int tile = blk;
        if (tile * 64 >= NA) return;
        ush* Hh = (ush*)smem;                       // 64*256 ush = 32768 B
        ush* segid = (ush*)(smem + 32768);          // 64 ush
        const MlpPack& P = A.P0;
        if (tid < 64) segid[tid] = A.rowseg[(size_t)tile * 64 + tid];

        // ---- layer 1: 32 -> 256, X direct from dense global queue ----
        {
            f32x4 acc[4][4];
            #pragma unroll
            for (int a = 0; a < 4; ++a)
                #pragma unroll
                for (int m = 0; m < 4; ++m) acc[a][m] = f32x4{0.f, 0.f, 0.f, 0.f};
            bf16x8 wh[4];
            #pragma unroll
            for (int a = 0; a < 4; ++a)
                wh[a] = *(const bf16x8*)(P.w1h + ((size_t)(wv * 4 + a) * 64 + lane) * 8);
            #pragma unroll
            for (int m = 0; m < 4; ++m) {
                const int gr = tile * 64 + 16 * m + r;
                bf16x8 xh = {0, 0, 0, 0, 0, 0, 0, 0};
                if (g < 2) xh = *(const bf16x8*)(A.Xq + (size_t)gr * 16 + 8 * g);
                #pragma unroll
                for (int a = 0; a < 4; ++a) acc[a][m] = MFMA(wh[a], xh, acc[a][m]);
            }
            #pragma unroll
            for (int a = 0; a < 4; ++a) {
                const int n0 = (wv * 4 + a) * 16 + 4 * g;
                const float4 bv = *(const float4*)(P.b1 + n0);
                #pragma unroll
                for (int m = 0; m < 4; ++m) {
                    const int row = 16 * m + r;
                    const float y0 = eluf_fast(acc[a][m][0] + bv.x);
                    const float y1 = eluf_fast(acc[a][m][1] + bv.y);
                    const float y2 = eluf_fast(acc[a][m][2] + bv.z);
                    const float y3 = eluf_fast(acc[a][m][3] + bv.w);
                    uint2 u; u.x = pkbf(y0, y1); u.y = pkbf(y2, y3);
                    *(uint2*)(Hh + row * 256 + HX(row, n0)) = u;
                }
            }
        }
        __syncthreads();

        // ---- layer 2: 256 -> 256 (in place) ----
        {
            f32x4 acc[4][4];
            #pragma unroll
            for (int a = 0; a < 4; ++a)
                #pragma unroll
                for (int m = 0; m < 4; ++m) acc[a][m] = f32x4{0.f, 0.f, 0.f, 0.f};
            #pragma unroll 1
            for (int kb = 0; kb < 8; ++kb) {
                bf16x8 wh[4];
                #pragma unroll
                for (int a = 0; a < 4; ++a)
                    wh[a] = *(const bf16x8*)(P.w2h + ((size_t)(kb * 16 + (wv * 4 + a)) * 64 + lane) * 8);
                #pragma unroll
                for (int m = 0; m < 4; ++m) {
                    const int row = 16 * m + r;
                    const int k0 = kb * 32 + 8 * g;
                    bf16x8 hh = *(const bf16x8*)(Hh + row * 256 + HX(row, k0));
                    #pragma unroll
                    for (int a = 0; a < 4; ++a) acc[a][m] = MFMA(wh[a], hh, acc[a][m]);
                }
            }
            __syncthreads();
            #pragma unroll
            for (int a = 0; a < 4; ++a) {
                const int n0 = (wv * 4 + a) * 16 + 4 * g;
                const float4 bv = *(const float4*)(P.b2 + n0);
                #pragma unroll
                for (int m = 0; m < 4; ++m) {
                    const int row = 16 * m + r;
                    const float y0 = eluf_fast(acc[a][m][0] + bv.x);
                    const float y1 = eluf_fast(acc[a][m][1] + bv.y);
                    const float y2 = eluf_fast(acc[a][m][2] + bv.z);
                    const float y3 = eluf_fast(acc[a][m][3] + bv.w);
                    uint2 u; u.x = pkbf(y0, y1); u.y = pkbf(y2, y3);
                    *(uint2*)(Hh + row * 256 + HX(row, n0)) = u;
                }
            }
        }
        __syncthreads();

        // ---- layer 3: 256 -> 128 ----
        f32x4 acc3[2][4];
        #pragma unroll
        for (int a = 0; a < 2; ++a)
            #pragma unroll
            for (int m = 0; m < 4; ++m) acc3[a][m] = f32x4{0.f, 0.f, 0.f, 0.f};
        #pragma unroll 1
        for (int kb = 0; kb < 8; ++kb) {
            bf16x8 wh[2];
            #pragma unroll
            for (int a = 0; a < 2; ++a)
                wh[a] = *(const bf16x8*)(P.w3h + ((size_t)(kb * 8 + (wv * 2 + a)) * 64 + lane) * 8);
            #pragma unroll
            for (int m = 0; m < 4; ++m) {
                const int row = 16 * m + r;
                const int k0 = kb * 32 + 8 * g;
                bf16x8 hh = *(const bf16x8*)(Hh + row * 256 + HX(row, k0));
                #pragma unroll
                for (int a = 0; a < 2; ++a) acc3[a][m] = MFMA(wh[a], hh, acc3[a][m]);
            }
        }
        __syncthreads();            // all Hh reads complete before aliasing as f1buf

        // ---- write y rows to LDS f1buf (f32, XOR-swizzled) ----
        float* f1buf = (float*)Hh;
        #pragma unroll
        for (int a = 0; a < 2; ++a) {
            const int n0 = (wv * 2 + a) * 16 + 4 * g;
            const float4 bv = *(const float4*)(P.b3 + n0);
            #pragma unroll
            for (int m = 0; m < 4; ++m) {
                const int row = 16 * m + r;
                float4 y;
                y.x = acc3[a][m][0] + bv.x;
                y.y = acc3[a][m][1] + bv.y;
                y.z = acc3[a][m][2] + bv.z;
                y.w = acc3[a][m][3] + bv.w;
                *(float4*)&f1buf[row * 128 + FX(row, n0)] = y;
            }
        }
        __syncthreads();

        // ---- segmented SUM pooling (cnt analytic): thread = (col, 32-row half).
        {
            const int c = tid & 127, h = tid >> 7;
            const int r0p = h * 32;
            float accS = 0.f;
            int cur = -1;
            #pragma unroll
            for (int j = 0; j < 32; ++j) {
                const int rl = r0p + j;
                const int sg = (int)segid[rl];
                if (sg != cur) {
                    if ((unsigned)cur < (unsigned)NROW)
                        atomicAdd(&A.sumG[(size_t)cur * 128 + c], accS);
                    cur = sg; accS = 0.f;
                }
                accS += f1buf[rl * 128 + FX(rl, c)];
            }
            if ((unsigned)cur < (unsigned)NROW)
                atomicAdd(&A.sumG[(size_t)cur * 128 + c], accS);
        }
    } else {
        // ================= f1 paths 0..2 (32-row tiles) =================
        const int pb = blk - 8192;
        const int p = pb >> 8;
        const int row0 = (pb & 255) * 32;
        ush* Xh = (ush*)smem;                        // 32*32 = 2048 B
        ush* Xl = (ush*)(smem + 2048);
        ush* Hh = (ush*)(smem + 4096);               // 32*256 = 16384 B
        ush* Hl = (ush*)(smem + 20480);
        float* UT = (float*)(smem + 36864);          // 32 floats
        const float* Xg = A.X[p];
        const MlpPack P = A.P[p];
        float* f1_out = A.f1[p];
        float* ut_out = A.ut[p];
        if (tid < 32) UT[tid] = 0.f;
        for (int idx = tid; idx < 32 * 32; idx += 256) {
            const int row = idx >> 5, k = idx & 31;
            float v = 0.f;
            if (k < 16) v = Xg[(size_t)(row0 + row) * 16 + k];
            const uint32 uv = __float_as_uint(v);
            Xh[idx] = (ush)(uv >> 16);
            const float rest = v - __uint_as_float(uv & 0xFFFF0000u);
            Xl[idx] = (ush)(__float_as_uint(rest) >> 16);
        }
        __syncthreads();
        f32x4 acc3[2][2];
        mlp3_core32(P, 1, Xh, Xl, Hh, Hl, acc3);

        float utp[2] = {0.f, 0.f};
        #pragma unroll
        for (int a = 0; a < 2; ++a) {
            const int n0 = (wv * 2 + a) * 16 + 4 * g;
            const float4 bv = *(const float4*)(P.b3 + n0);
            const float4 av = *(const float4*)(attn + n0);
            #pragma unroll
            for (int m = 0; m < 2; ++m) {
                float4 y;
                y.x = acc3[a][m][0] + bv.x;
                y.y = acc3[a][m][1] + bv.y;
                y.z = acc3[a][m][2] + bv.z;
                y.w = acc3[a][m][3] + bv.w;
                *(float4*)&f1_out[(size_t)(row0 + 16 * m + r) * OUTc + n0] = y;
                utp[m] += y.x * av.x + y.y * av.y + y.z * av.z + y.w * av.w;
            }
        }
        #pragma unroll
        for (int m = 0; m < 2; ++m) {
            float v = utp[m];
            v += __shfl_xor(v, 16);
            v += __shfl_xor(v, 32);
            if (lane < 16) atomicAdd(&UT[16 * m + r], v);
        }
        __syncthreads();
        if (tid < 32) ut_out[row0 + tid] = UT[tid];
    }
}

// ---------------------------------------------------------------------------
// MLP4 path (depends on edge results): 32 rows/block, finalizes x2 inline.
// cnt is analytic: active rows each contribute 1; inactive contribute [f1z!=0].
// ---------------------------------------------------------------------------
__global__ __launch_bounds__(256, 3) void p3_kernel(
    MlpPack P, const float* __restrict__ attn,
    const float* __restrict__ sumG,
    const int* __restrict__ counts, const float* __restrict__ f1z,
    float* __restrict__ f1_out, float* __restrict__ ut_out)
{
    __shared__ ush Xh[32 * 128], Xl[32 * 128];
    __shared__ ush Hh[32 * 256], Hl[32 * 256];
    __shared__ float UT[32];
    const int tid = threadIdx.x;
    const int row0 = blockIdx.x * 32;
    if (tid < 32) UT[tid] = 0.f;
    for (int idx = tid; idx < 32 * 128; idx += 256) {
        const int row = idx >> 7, k = idx & 127;
        const size_t rid = (size_t)(row0 + row);
        const float na = (float)counts[rid];
        const float nz = 64.f - na;
        const float fz = f1z[k];
        const float v = (sumG[rid * 128 + k] + nz * fz)
                      / (na + nz * ((fz != 0.f) ? 1.f : 0.f));
        const uint32 uv = __float_as_uint(v);
        Xh[idx] = (ush)(uv >> 16);
        const float rest = v - __uint_as_float(uv & 0xFFFF0000u);
        Xl[idx] = (ush)(__float_as_uint(rest) >> 16);
    }
    __syncthreads();
    f32x4 acc3[2][2];
    mlp3_core32(P, 4, Xh, Xl, Hh, Hl, acc3);

    const int wv = tid >> 6, lane = tid & 63, r = lane & 15, g = lane >> 4;
    float utp[2] = {0.f, 0.f};
    #pragma unroll
    for (int a = 0; a < 2; ++a) {
        const int n0 = (wv * 2 + a) * 16 + 4 * g;
        const float4 bv = *(const float4*)(P.b3 + n0);
        const float4 av = *(const float4*)(attn + n0);
        #pragma unroll
        for (int m = 0; m < 2; ++m) {
            float4 y;
            y.x = acc3[a][m][0] + bv.x;
            y.y = acc3[a][m][1] + bv.y;
            y.z = acc3[a][m][2] + bv.z;
            y.w = acc3[a][m][3] + bv.w;
            *(float4*)&f1_out[(size_t)(row0 + 16 * m + r) * OUTc + n0] = y;
            utp[m] += y.x * av.x + y.y * av.y + y.z * av.z + y.w * av.w;
        }
    }
    #pragma unroll
    for (int m = 0; m < 2; ++m) {
        float v = utp[m];
        v += __shfl_xor(v, 16);
        v += __shfl_xor(v, 32);
        if (lane < 16) atomicAdd(&UT[16 * m + r], v);
    }
    __syncthreads();
    if (tid < 32) ut_out[row0 + tid] = UT[tid];
}

// ---------------------------------------------------------------------------
// combine with inline per-batch softmax: block = (b, 32-row chunk).
// ---------------------------------------------------------------------------
__global__ __launch_bounds__(256) void combine2_kernel(
    const float* __restrict__ uts,
    const float* __restrict__ pre_f1, const float* __restrict__ sub_f1,
    const float* __restrict__ self_f1, const float* __restrict__ ma_f2,
    float* __restrict__ out)
{
    __shared__ float sc[4 * NOPc];
    __shared__ float red[256];
    const int b = blockIdx.x >> 4, chunk = blockIdx.x & 15;
    const int t = threadIdx.x;
    const float* put = uts + 0 * NROW + (size_t)b * NOPc;
    const float* sut = uts + 1 * NROW + (size_t)b * NOPc;
    const float* eut = uts + 2 * NROW + (size_t)b * NOPc;
    const float* mut = uts + 3 * NROW + (size_t)b * NOPc;
    for (int i = t; i < NOPc; i += 256) {
        const float se = eut[i];
        const float s0 = put[i] + se, s1 = sut[i] + se, s2 = se + se, s3 = mut[i] + se;
        sc[0 * NOPc + i] = s0 > 0.f ? s0 : 0.2f * s0;
        sc[1 * NOPc + i] = s1 > 0.f ? s1 : 0.2f * s1;
        sc[2 * NOPc + i] = s2 > 0.f ? s2 : 0.2f * s2;
        sc[3 * NOPc + i] = s3 > 0.f ? s3 : 0.2f * s3;
    }
    __syncthreads();
    float mx = -INFINITY;
    for (int idx = t; idx < 4 * NOPc; idx += 256) mx = fmaxf(mx, sc[idx]);
    red[t] = mx;
    __syncthreads();
    for (int s = 128; s > 0; s >>= 1) { if (t < s) red[t] = fmaxf(red[t], red[t + s]); __syncthreads(); }
    mx = red[0];
    __syncthreads();
    float ps = 0.f;
    for (int idx = t; idx < 4 * NOPc; idx += 256) {
        const float e = expf(sc[idx] - mx);
        sc[idx] = e;
        ps += e;
    }
    red[t] = ps;
    __syncthreads();
    for (int s = 128; s > 0; s >>= 1) { if (t < s) red[t] += red[t + s]; __syncthreads(); }
    const float invZ = 1.f / red[0];

    const size_t base4 = (size_t)b * 16384 + (size_t)chunk * 1024;   // float4 units
    #pragma unroll
    for (int k = 0; k < 4; ++k) {
        const size_t e4 = base4 + k * 256 + t;
        const int i = (int)((e4 >> 5) & 511);
        const float a0 = sc[0 * NOPc + i] * invZ;
        const float a1 = sc[1 * NOPc + i] * invZ;
        const float a2 = sc[2 * NOPc + i] * invZ;
        const float a3 = sc[3 * NOPc + i] * invZ;
        const float4 vp = ((const float4*)pre_f1)[e4];
        const float4 vs = ((const float4*)sub_f1)[e4];
        const float4 ve = ((const float4*)self_f1)[e4];
        const float4 vm = ((const float4*)ma_f2)[e4];
        float4 o;
        o.x = 1.f / (1.f + expf(-(a0 * vp.x + a1 * vs.x + a2 * ve.x + a3 * vm.x)));
        o.y = 1.f / (1.f + expf(-(a0 * vp.y + a1 * vs.y + a2 * ve.y + a3 * vm.y)));
        o.z = 1.f / (1.f + expf(-(a0 * vp.z + a1 * vs.z + a2 * ve.z + a3 * vm.z)));
        o.w = 1.f / (1.f + expf(-(a0 * vp.w + a1 * vs.w + a2 * ve.w + a3 * vm.w)));
        ((float4*)out)[e4] = o;
    }
}

extern "C" void kernel_launch(void* const* d_in, const int* in_sizes, int n_in,
                              void* d_out, int out_size, void* d_ws, size_t ws_size,
                              hipStream_t stream) {
    const float* op      = (const float*)d_in[0];
    const float* ma      = (const float*)d_in[1];
    const float* eg      = (const float*)d_in[2];
    const int*   ma_adj  = (const int*)d_in[3];
    const int*   pre_adj = (const int*)d_in[4];
    const int*   sub_adj = (const int*)d_in[5];
    const int*   bidx    = (const int*)d_in[6];
    const float* attn    = (const float*)d_in[7];
    float* out = (float*)d_out;
    const float* Wraw[5][6];
    for (int m = 0; m < 5; ++m)
        for (int j = 0; j < 6; ++j)
            Wraw[m][j] = (const float*)d_in[8 + 6 * m + j];

    // ---- workspace layout ----
    float* wsf = (float*)d_ws;
    float* pre_agg = wsf;  wsf += (size_t)NROW * 16;
    float* sub_agg = wsf;  wsf += (size_t)NROW * 16;
    float* pre_f1  = wsf;  wsf += (size_t)NROW * OUTc;
    float* sub_f1  = wsf;  wsf += (size_t)NROW * OUTc;
    float* self_f1 = wsf;  wsf += (size_t)NROW * OUTc;
    float* ma_f2   = wsf;  wsf += (size_t)NROW * OUTc;
    float* uts     = wsf;  wsf += (size_t)4 * NROW;
    float* f1z     = wsf;  wsf += 128;
    float* sumG    = wsf;  wsf += (size_t)NROW * 128;
    int*   counts  = (int*)wsf;   wsf += NROW;
    int*   bases   = (int*)wsf;   wsf += NROW;
    int*   natot   = (int*)wsf;   wsf += 16;
    ush*   rowseg  = (ush*)wsf;   wsf += NEMAX / 2;
    ush*   Xq      = (ush*)wsf;   wsf += (size_t)NEMAX * 8;   // NEMAX rows * 16 ush
    ush*   packp   = (ush*)wsf;

    PrepArgs pa;
    MlpPack pk[5];
    for (int m = 0; m < 5; ++m) {
        const int kre[3] = { (m == 4 ? 128 : 16), 256, 256 };
        const int kbn[3] = { (m == 4 ? 4 : 1), 8, 8 };
        const int nbn[3] = { 16, 16, 8 };
        const ush* dh[3]; const ush* dl[3];
        for (int j = 0; j < 3; ++j) {
            const int id = m * 3 + j;
            pa.d[id].src = Wraw[m][2 * j];
            pa.d[id].kreal = kre[j];
            pa.d[id].kbn = kbn[j];
            pa.d[id].nbn = nbn[j];
            const int cnt = kbn[j] * nbn[j] * 512;
            pa.d[id].dh = packp; dh[j] = packp; packp += cnt;
            pa.d[id].dl = packp; dl[j] = packp; packp += cnt;
        }
        pk[m].w1h = dh[0]; pk[m].w1l = dl[0];
        pk[m].w2h = dh[1]; pk[m].w2l = dl[1];
        pk[m].w3h = dh[2]; pk[m].w3l = dl[2];
        pk[m].b1 = Wraw[m][1]; pk[m].b2 = Wraw[m][3]; pk[m].b3 = Wraw[m][5];
    }
    pa.op = op; pa.pre_adj = pre_adj; pa.sub_adj = sub_adj; pa.ma_adj = ma_adj;
    pa.bidx = bidx;
    pa.pre_agg = pre_agg; pa.sub_agg = sub_agg; pa.counts = counts;
    pa.z_b1 = Wraw[0][1]; pa.z_w2 = Wraw[0][2]; pa.z_b2 = Wraw[0][3];
    pa.z_w3 = Wraw[0][4]; pa.z_b3 = Wraw[0][5];
    pa.f1z = f1z;

    EF1Args ea;
    ea.Xq = Xq; ea.rowseg = rowseg; ea.natot = natot; ea.P0 = pk[0];
    ea.sumG = sumG;
    ea.X[0] = pre_agg; ea.X[1] = sub_agg; ea.X[2] = op;
    ea.P[0] = pk[1];   ea.P[1] = pk[2];   ea.P[2] = pk[3];
    ea.f1[0] = pre_f1; ea.f1[1] = sub_f1; ea.f1[2] = self_f1;
    ea.ut[0] = uts + 0 * NROW;
    ea.ut[1] = uts + 1 * NROW;
    ea.ut[2] = uts + 2 * NROW;

    prep_kernel<<<dim3(960 + NROW + 1), 256, 0, stream>>>(pa);
    scan_kernel<<<1, 1024, 0, stream>>>(counts, bases, natot, Xq, rowseg);
    scatter_kernel<<<dim3(NROW / 4), 256, 0, stream>>>(ma, eg, ma_adj, bidx, bases,
                                                       Xq, rowseg, sumG);
    edge_f1_kernel<<<dim3(8192 + 768), 256, 0, stream>>>(ea, attn);
    p3_kernel<<<dim3(256), 256, 0, stream>>>(pk[4], attn, sumG, counts, f1z,
                                             ma_f2, uts + 3 * NROW);
    combine2_kernel<<<dim3(NBb * 16), 256, 0, stream>>>(uts, pre_f1, sub_f1, self_f1, ma_f2, out);
}

// Round 12
// 159.993 us; speedup vs baseline: 1.1829x; 1.0310x over previous
//
#include <hip/hip_runtime.h>
#include <math.h>

#define NBb  16
#define NOPc 512
#define NMAc 64
#define HIDc 256
#define OUTc 128
#define NROW (NBb * NOPc)          // 8192 (b,i) rows
#define NEMAX (NROW * NMAc)        // 524288 max edges

// LDS swizzles: H row stride 512B is bank-aligned; fold 4 row bits into col.
#define HX(row, col) ((col) ^ (8 * ((row) & 15)))    // ush units (H buffers)
#define FX(row, col) ((col) ^ (4 * ((row) & 15)))    // f32 units (f1buf)

typedef unsigned int uint32;
typedef unsigned short ush;
typedef __attribute__((ext_vector_type(8))) short bf16x8;
typedef __attribute__((ext_vector_type(4))) float f32x4;

__device__ __forceinline__ ush f2bf(float v) {
    uint32 u = __float_as_uint(v);
    u += 0x7FFFu + ((u >> 16) & 1u);
    return (ush)(u >> 16);
}
__device__ __forceinline__ float bf2f(ush b) { return __uint_as_float(((uint32)b) << 16); }
__device__ __forceinline__ float eluf(float x) { return x > 0.f ? x : expm1f(x); }
__device__ __forceinline__ float eluf_fast(float x) { return x > 0.f ? x : __expf(x) - 1.f; }
// pack two floats' truncated bf16 into one u32: low = bf16(a), high = bf16(b)
__device__ __forceinline__ uint32 pkbf(float a, float b) {
    return __builtin_amdgcn_perm(__float_as_uint(b), __float_as_uint(a), 0x07060302u);
}
__device__ __forceinline__ uint32 pkbf_rne(float a, float b) {
    return (uint32)f2bf(a) | ((uint32)f2bf(b) << 16);
}
// truncation hi/lo split of 2 floats (residual captured exactly by lo plane)
__device__ __forceinline__ void split2(float a, float b, uint32& hp, uint32& lp) {
    const uint32 ua = __float_as_uint(a), ub = __float_as_uint(b);
    hp = __builtin_amdgcn_perm(ub, ua, 0x07060302u);
    const float ra = a - __uint_as_float(ua & 0xFFFF0000u);
    const float rb = b - __uint_as_float(ub & 0xFFFF0000u);
    lp = __builtin_amdgcn_perm(__float_as_uint(rb), __float_as_uint(ra), 0x07060302u);
}

#define MFMA(A, B, C) __builtin_amdgcn_mfma_f32_16x16x32_bf16((A), (B), (C), 0, 0, 0)

// pack[((kb*nbn + nb)*64 + lane)*8 + e] = W[kb*32 + 8*(lane>>4) + e][nb*16 + (lane&15)]
struct MlpPack {
    const ush *w1h, *w1l, *w2h, *w2l, *w3h, *w3l;
    const float *b1, *b2, *b3;
};

// ---------------------------------------------------------------------------
// Hi/lo (bf16x3) 3-layer core, 32-row tile. Bias pre-loaded into MFMA C-in;
// acc3 returned WITH bias.
// ---------------------------------------------------------------------------
__device__ __forceinline__ void mlp3_core32(
    const MlpPack& P, const int KB1,
    const ush* Xh, const ush* Xl, ush* Hh, ush* Hl, f32x4 acc3[2][2])
{
    const int tid = threadIdx.x;
    const int wv = tid >> 6, lane = tid & 63, r = lane & 15, g = lane >> 4;
    const int KX = KB1 * 32;

    // layer 1: KX -> 256
    {
        f32x4 acc[4][2];
        #pragma unroll
        for (int a = 0; a < 4; ++a) {
            const float4 bv = *(const float4*)(P.b1 + (wv * 4 + a) * 16 + 4 * g);
            #pragma unroll
            for (int m = 0; m < 2; ++m) acc[a][m] = f32x4{bv.x, bv.y, bv.z, bv.w};
        }
        #pragma unroll 1
        for (int kb = 0; kb < KB1; ++kb) {
            bf16x8 wh[4], wl[4];
            #pragma unroll
            for (int a = 0; a < 4; ++a) {
                const size_t o = ((size_t)(kb * 16 + (wv * 4 + a)) * 64 + lane) * 8;
                wh[a] = *(const bf16x8*)(P.w1h + o);
                wl[a] = *(const bf16x8*)(P.w1l + o);
            }
            #pragma unroll
            for (int m = 0; m < 2; ++m) {
                const int row = 16 * m + r;
                const int ki = kb * 32 + 8 * g;
                bf16x8 xh = *(const bf16x8*)(Xh + row * KX + ki);
                bf16x8 xl = *(const bf16x8*)(Xl + row * KX + ki);
                #pragma unroll
                for (int a = 0; a < 4; ++a) {
                    acc[a][m] = MFMA(wh[a], xh, acc[a][m]);
                    acc[a][m] = MFMA(wh[a], xl, acc[a][m]);
                    acc[a][m] = MFMA(wl[a], xh, acc[a][m]);
                }
            }
        }
        #pragma unroll
        for (int a = 0; a < 4; ++a) {
            const int n0 = (wv * 4 + a) * 16 + 4 * g;
            #pragma unroll
            for (int m = 0; m < 2; ++m) {
                const int row = 16 * m + r;
                const float y0 = eluf_fast(acc[a][m][0]);
                const float y1 = eluf_fast(acc[a][m][1]);
                const float y2 = eluf_fast(acc[a][m][2]);
                const float y3 = eluf_fast(acc[a][m][3]);
                uint2 uh, ul;
                split2(y0, y1, uh.x, ul.x);
                split2(y2, y3, uh.y, ul.y);
                const int idx = row * 256 + HX(row, n0);
                *(uint2*)(Hh + idx) = uh;
                *(uint2*)(Hl + idx) = ul;
            }
        }
    }
    __syncthreads();

    // layer 2: 256 -> 256 (in place)
    {
        f32x4 acc[4][2];
        #pragma unroll
        for (int a = 0; a < 4; ++a) {
            const float4 bv = *(const float4*)(P.b2 + (wv * 4 + a) * 16 + 4 * g);
            #pragma unroll
            for (int m = 0; m < 2; ++m) acc[a][m] = f32x4{bv.x, bv.y, bv.z, bv.w};
        }
        #pragma unroll 1
        for (int kb = 0; kb < 8; ++kb) {
            bf16x8 wh[4], wl[4];
            #pragma unroll
            for (int a = 0; a < 4; ++a) {
                const size_t o = ((size_t)(kb * 16 + (wv * 4 + a)) * 64 + lane) * 8;
                wh[a] = *(const bf16x8*)(P.w2h + o);
                wl[a] = *(const bf16x8*)(P.w2l + o);
            }
            #pragma unroll
            for (int m = 0; m < 2; ++m) {
                const int row = 16 * m + r;
                const int k0 = kb * 32 + 8 * g;
                const int idx = row * 256 + HX(row, k0);
                bf16x8 hh = *(const bf16x8*)(Hh + idx);
                bf16x8 hl = *(const bf16x8*)(Hl + idx);
                #pragma unroll
                for (int a = 0; a < 4; ++a) {
                    acc[a][m] = MFMA(wh[a], hh, acc[a][m]);
                    acc[a][m] = MFMA(wh[a], hl, acc[a][m]);
                    acc[a][m] = MFMA(wl[a], hh, acc[a][m]);
                }
            }
        }
        __syncthreads();
        #pragma unroll
        for (int a = 0; a < 4; ++a) {
            const int n0 = (wv * 4 + a) * 16 + 4 * g;
            #pragma unroll
            for (int m = 0; m < 2; ++m) {
                const int row = 16 * m + r;
                const float y0 = eluf_fast(acc[a][m][0]);
                const float y1 = eluf_fast(acc[a][m][1]);
                const float y2 = eluf_fast(acc[a][m][2]);
                const float y3 = eluf_fast(acc[a][m][3]);
                uint2 uh, ul;
                split2(y0, y1, uh.x, ul.x);
                split2(y2, y3, uh.y, ul.y);
                const int idx = row * 256 + HX(row, n0);
                *(uint2*)(Hh + idx) = uh;
                *(uint2*)(Hl + idx) = ul;
            }
        }
    }
    __syncthreads();

    // layer 3: 256 -> 128 (acc3 includes bias)
    {
        #pragma unroll
        for (int a = 0; a < 2; ++a) {
            const float4 bv = *(const float4*)(P.b3 + (wv * 2 + a) * 16 + 4 * g);
            #pragma unroll
            for (int m = 0; m < 2; ++m) acc3[a][m] = f32x4{bv.x, bv.y, bv.z, bv.w};
        }
        #pragma unroll 1
        for (int kb = 0; kb < 8; ++kb) {
            bf16x8 wh[2], wl[2];
            #pragma unroll
            for (int a = 0; a < 2; ++a) {
                const size_t o = ((size_t)(kb * 8 + (wv * 2 + a)) * 64 + lane) * 8;
                wh[a] = *(const bf16x8*)(P.w3h + o);
                wl[a] = *(const bf16x8*)(P.w3l + o);
            }
            #pragma unroll
            for (int m = 0; m < 2; ++m) {
                const int row = 16 * m + r;
                const int k0 = kb * 32 + 8 * g;
                const int idx = row * 256 + HX(row, k0);
                bf16x8 hh = *(const bf16x8*)(Hh + idx);
                bf16x8 hl = *(const bf16x8*)(Hl + idx);
                #pragma unroll
                for (int a = 0; a < 2; ++a) {
                    acc3[a][m] = MFMA(wh[a], hh, acc3[a][m]);
                    acc3[a][m] = MFMA(wh[a], hl, acc3[a][m]);
                    acc3[a][m] = MFMA(wl[a], hh, acc3[a][m]);
                }
            }
        }
    }
}

// ---------------------------------------------------------------------------
// count: ma-edge count per (b,i). 4 rids per block (one per wave).
// ---------------------------------------------------------------------------
__global__ __launch_bounds__(256) void count_kernel(const int* __restrict__ ma_adj,
                                                    const int* __restrict__ bidx,
                                                    int* __restrict__ counts)
{
    const int tid = threadIdx.x;
    const int rid = blockIdx.x * 4 + (tid >> 6);
    const int lane = tid & 63;
    const int b = rid >> 9, i = rid & 511;
    const int bi = bidx[b];
    const int active = (ma_adj[((size_t)bi * NOPc + i) * NMAc + lane] != 0) ? 1 : 0;
    const unsigned long long mk = __ballot(active);
    if (lane == 0) counts[rid] = (int)__popcll(mk);
}

// ---------------------------------------------------------------------------
// scan: exclusive prefix over counts[8192] -> bases, natot; zero/sentinel pad.
// ---------------------------------------------------------------------------
__global__ __launch_bounds__(1024) void scan_kernel(const int* __restrict__ counts,
                                                    int* __restrict__ bases,
                                                    int* __restrict__ natot,
                                                    ush* __restrict__ Xq,
                                                    ush* __restrict__ rowseg)
{
    __shared__ int tot[1024];
    const int t = threadIdx.x;
    int loc[8];
    int s = 0;
    #pragma unroll
    for (int k = 0; k < 8; ++k) { loc[k] = s; s += counts[t * 8 + k]; }
    tot[t] = s;
    __syncthreads();
    for (int off = 1; off < 1024; off <<= 1) {
        const int v = (t >= off) ? tot[t - off] : 0;
        __syncthreads();
        tot[t] += v;
        __syncthreads();
    }
    const int base = tot[t] - s;   // exclusive
    #pragma unroll
    for (int k = 0; k < 8; ++k) bases[t * 8 + k] = base + loc[k];
    const int NA = tot[1023];
    if (t == 0) *natot = NA;
    __syncthreads();
    const int NApad = (NA + 63) & ~63;
    for (int idx = NA * 16 + t; idx < NApad * 16; idx += 1024) Xq[idx] = 0;
    for (int idx = NA + t; idx < NApad; idx += 1024) rowseg[idx] = (ush)0xFFFFu;
}

// ---------------------------------------------------------------------------
// prep: pack [0,960) + agg (8 i's/block, op staged in LDS) [960,1984) +
// f1z (1984) + scatter [1985,4033).
// ---------------------------------------------------------------------------
struct PackDesc { const float* src; ush* dh; ush* dl; int kreal; int kbn; int nbn; };
struct PrepArgs {
    PackDesc d[15];
    const float* op; const int* pre_adj; const int* sub_adj; const int* ma_adj;
    const int* bidx;
    float* pre_agg; float* sub_agg;
    const float *z_b1, *z_w2, *z_b2, *z_w3, *z_b3;
    float* f1z;
    const float* ma; const float* eg; const int* bases;
    ush* Xq; ush* rowseg; float* sumG;
};

__global__ __launch_bounds__(256) void prep_kernel(PrepArgs A)
{
    __shared__ float shmem[9216];      // 36 KB: opS [512*17] + red [512]
    const int blk = blockIdx.x;
    const int t = threadIdx.x;
    if (blk < 960) {
        // ---- weight pack ----
        const PackDesc d = A.d[blk >> 6];
        const int sub = blk & 63;
        const int total = d.kbn * d.nbn * 512;
        const int N = d.nbn * 16;
        for (int idx = sub * 256 + t; idx < total; idx += 64 * 256) {
            const int e = idx & 7;
            const int l = (idx >> 3) & 63;
            const int t2 = idx >> 9;
            const int nb = t2 % d.nbn;
            const int kb = t2 / d.nbn;
            const int k = kb * 32 + ((l >> 4) << 3) + e;
            const int n = nb * 16 + (l & 15);
            const float v = (k < d.kreal) ? d.src[(size_t)k * N + n] : 0.f;
            const ush hi = f2bf(v);
            d.dh[idx] = hi;
            d.dl[idx] = f2bf(v - bf2f(hi));
        }
    } else if (blk < 1984) {
        // ---- agg: block = (b, group of 8 i's); op[b] staged in LDS ----
        const int e = blk - 960;
        const int b = e >> 6;
        const int i0 = (e & 63) * 8;
        const int bi = A.bidx[b];
        float* opS = shmem;                 // [512][17]
        float* red = shmem + 8704;          // [2][256]
        {
            const float4* op4 = (const float4*)(A.op + (size_t)b * 8192);
            for (int idx4 = t; idx4 < 2048; idx4 += 256) {
                const float4 v = op4[idx4];
                const int row = idx4 >> 2, d0 = (idx4 & 3) * 4;
                float* dst = &opS[row * 17 + d0];
                dst[0] = v.x; dst[1] = v.y; dst[2] = v.z; dst[3] = v.w;
            }
        }
        __syncthreads();
        const int d = t & 15, g = t >> 4;
        for (int ii = 0; ii < 8; ++ii) {
            const int i = i0 + ii;
            const int4* pr4 = (const int4*)(A.pre_adj + ((size_t)bi * NOPc + i) * NOPc);
            const int4* sr4 = (const int4*)(A.sub_adj + ((size_t)bi * NOPc + i) * NOPc);
            float ap = 0.f, as = 0.f;
            #pragma unroll 2
            for (int j4 = g; j4 < 128; j4 += 16) {
                const int4 p = pr4[j4];
                const int4 s = sr4[j4];
                const int jb = j4 << 2;
                const float v0 = opS[(jb + 0) * 17 + d];
                const float v1 = opS[(jb + 1) * 17 + d];
                const float v2 = opS[(jb + 2) * 17 + d];
                const float v3 = opS[(jb + 3) * 17 + d];
                if (p.x) ap += v0;  if (p.y) ap += v1;  if (p.z) ap += v2;  if (p.w) ap += v3;
                if (s.x) as += v0;  if (s.y) as += v1;  if (s.z) as += v2;  if (s.w) as += v3;
            }
            red[g * 16 + d] = ap;
            red[256 + g * 16 + d] = as;
            __syncthreads();
            if (t < 32) {
                const int which = t >> 4, dd = t & 15;
                float s = 0.f;
                #pragma unroll
                for (int gg = 0; gg < 16; ++gg) s += red[which * 256 + gg * 16 + dd];
                float* dst = which ? A.sub_agg : A.pre_agg;
                dst[((size_t)b * NOPc + i) * 16 + dd] = s;
            }
            __syncthreads();
        }
    } else if (blk == 1984) {
        // ---- f1z = MLP0(0) in raw f32 ----
        shmem[t] = eluf(A.z_b1[t]);
        __syncthreads();
        float acc = A.z_b2[t];
        for (int k = 0; k < 256; ++k) acc += shmem[k] * A.z_w2[(size_t)k * 256 + t];
        __syncthreads();
        shmem[256 + t] = eluf(acc);
        __syncthreads();
        if (t < 128) {
            float a = A.z_b3[t];
            for (int k = 0; k < 256; ++k) a += shmem[256 + k] * A.z_w3[(size_t)k * 128 + t];
            A.f1z[t] = a;
        }
    } else {
        // ---- scatter: dense bf16 edge rows + rowseg; zero sumG ----
        const int rid = (blk - 1985) * 4 + (t >> 6);
        const int lane = t & 63;
        const int b = rid >> 9, i = rid & 511;
        const int bi = A.bidx[b];
        const int act = (A.ma_adj[((size_t)bi * NOPc + i) * NMAc + lane] != 0) ? 1 : 0;
        const unsigned long long mk = __ballot(act);
        if (act) {
            const int pos = A.bases[rid] + (int)__popcll(mk & ((1ull << lane) - 1ull));
            const float4* mp = (const float4*)(A.ma + ((size_t)b * NMAc + lane) * 8);
            const float4* ep = (const float4*)(A.eg + (((size_t)b * NOPc + i) * NMAc + lane) * 8);
            const float4 m0 = mp[0], m1 = mp[1], e0 = ep[0], e1 = ep[1];
            uint4 u0, u1;
            u0.x = pkbf_rne(m0.x, m0.y); u0.y = pkbf_rne(m0.z, m0.w);
            u0.z = pkbf_rne(m1.x, m1.y); u0.w = pkbf_rne(m1.z, m1.w);
            u1.x = pkbf_rne(e0.x, e0.y); u1.y = pkbf_rne(e0.z, e0.w);
            u1.z = pkbf_rne(e1.x, e1.y); u1.w = pkbf_rne(e1.z, e1.w);
            uint4* dst = (uint4*)(A.Xq + (size_t)pos * 16);
            dst[0] = u0;
            dst[1] = u1;
            A.rowseg[pos] = (ush)rid;
        }
        A.sumG[(size_t)rid * 128 + lane] = 0.f;
        A.sumG[(size_t)rid * 128 + 64 + lane] = 0.f;
    }
}

// ---------------------------------------------------------------------------
// Fused kernel: blocks [0,8192) = edge MLP0 tiles; [8192, 8960) = f1 paths.
// ---------------------------------------------------------------------------
struct EF1Args {
    const ush* Xq; const ush* rowseg; const int* natot; MlpPack P0;
    float* sumG;
    const float* X[3]; MlpPack P[3]; float* f1[3]; float* ut[3];
};

__global__ __launch_bounds__(256, 4) void edge_f1_kernel(EF1Args A, const float* __restrict__ attn)
{
    __shared__ unsigned char smem[36992];
    const int blk = blockIdx.x;
    const int tid = threadIdx.x;
    const int wv = tid >> 6, lane = tid & 63, r = lane & 15, g = lane >> 4;

    if (blk < 8192) {
        // ================= edge path =================
        const int NA = *A.natot;
        const int tile = blk;
        if (tile * 64 >= NA) return;
        ush* Hh = (ush*)smem;                       // 64*256 ush = 32768 B
        ush* segid = (ush*)(smem + 32768);          // 64 ush
        const MlpPack& P = A.P0;
        if (tid < 64) segid[tid] = A.rowseg[(size_t)tile * 64 + tid];

        // ---- layer 1: 32 -> 256, X direct from dense global queue ----
        {
            f32x4 acc[4][4];
            #pragma unroll
            for (int a = 0; a < 4; ++a) {
                const float4 bv = *(const float4*)(P.b1 + (wv * 4 + a) * 16 + 4 * g);
                #pragma unroll
                for (int m = 0; m < 4; ++m) acc[a][m] = f32x4{bv.x, bv.y, bv.z, bv.w};
            }
            bf16x8 wh[4];
            #pragma unroll
            for (int a = 0; a < 4; ++a)
                wh[a] = *(const bf16x8*)(P.w1h + ((size_t)(wv * 4 + a) * 64 + lane) * 8);
            #pragma unroll
            for (int m = 0; m < 4; ++m) {
                const int gr = tile * 64 + 16 * m + r;
                bf16x8 xh = {0, 0, 0, 0, 0, 0, 0, 0};
                if (g < 2) xh = *(const bf16x8*)(A.Xq + (size_t)gr * 16 + 8 * g);
                #pragma unroll
                for (int a = 0; a < 4; ++a) acc[a][m] = MFMA(wh[a], xh, acc[a][m]);
            }
            #pragma unroll
            for (int a = 0; a < 4; ++a) {
                const int n0 = (wv * 4 + a) * 16 + 4 * g;
                #pragma unroll
                for (int m = 0; m < 4; ++m) {
                    const int row = 16 * m + r;
                    const float y0 = eluf_fast(acc[a][m][0]);
                    const float y1 = eluf_fast(acc[a][m][1]);
                    const float y2 = eluf_fast(acc[a][m][2]);
                    const float y3 = eluf_fast(acc[a][m][3]);
                    uint2 u; u.x = pkbf(y0, y1); u.y = pkbf(y2, y3);
                    *(uint2*)(Hh + row * 256 + HX(row, n0)) = u;
                }
            }
        }
        __syncthreads();

        // ---- layer 2: 256 -> 256 (in place) ----
        {
            f32x4 acc[4][4];
            #pragma unroll
            for (int a = 0; a < 4; ++a) {
                const float4 bv = *(const float4*)(P.b2 + (wv * 4 + a) * 16 + 4 * g);
                #pragma unroll
                for (int m = 0; m < 4; ++m) acc[a][m] = f32x4{bv.x, bv.y, bv.z, bv.w};
            }
            #pragma unroll 1
            for (int kb = 0; kb < 8; ++kb) {
                bf16x8 wh[4];
                #pragma unroll
                for (int a = 0; a < 4; ++a)
                    wh[a] = *(const bf16x8*)(P.w2h + ((size_t)(kb * 16 + (wv * 4 + a)) * 64 + lane) * 8);
                #pragma unroll
                for (int m = 0; m < 4; ++m) {
                    const int row = 16 * m + r;
                    const int k0 = kb * 32 + 8 * g;
                    bf16x8 hh = *(const bf16x8*)(Hh + row * 256 + HX(row, k0));
                    #pragma unroll
                    for (int a = 0; a < 4; ++a) acc[a][m] = MFMA(wh[a], hh, acc[a][m]);
                }
            }
            __syncthreads();
            #pragma unroll
            for (int a = 0; a < 4; ++a) {
                const int n0 = (wv * 4 + a) * 16 + 4 * g;
                #pragma unroll
                for (int m = 0; m < 4; ++m) {
                    const int row = 16 * m + r;
                    const float y0 = eluf_fast(acc[a][m][0]);
                    const float y1 = eluf_fast(acc[a][m][1]);
                    const float y2 = eluf_fast(acc[a][m][2]);
                    const float y3 = eluf_fast(acc[a][m][3]);
                    uint2 u; u.x = pkbf(y0, y1); u.y = pkbf(y2, y3);
                    *(uint2*)(Hh + row * 256 + HX(row, n0)) = u;
                }
            }
        }
        __syncthreads();

        // ---- layer 3: 256 -> 128 (acc includes bias) ----
        f32x4 acc3[2][4];
        #pragma unroll
        for (int a = 0; a < 2; ++a) {
            const float4 bv = *(const float4*)(P.b3 + (wv * 2 + a) * 16 + 4 * g);
            #pragma unroll
            for (int m = 0; m < 4; ++m) acc3[a][m] = f32x4{bv.x, bv.y, bv.z, bv.w};
        }
        #pragma unroll 1
        for (int kb = 0; kb < 8; ++kb) {
            bf16x8 wh[2];
            #pragma unroll
            for (int a = 0; a < 2; ++a)
                wh[a] = *(const bf16x8*)(P.w3h + ((size_t)(kb * 8 + (wv * 2 + a)) * 64 + lane) * 8);
            #pragma unroll
            for (int m = 0; m < 4; ++m) {
                const int row = 16 * m + r;
                const int k0 = kb * 32 + 8 * g;
                bf16x8 hh = *(const bf16x8*)(Hh + row * 256 + HX(row, k0));
                #pragma unroll
                for (int a = 0; a < 2; ++a) acc3[a][m] = MFMA(wh[a], hh, acc3[a][m]);
            }
        }
        __syncthreads();            // all Hh reads complete before aliasing as f1buf

        // ---- write y rows to LDS f1buf (f32, XOR-swizzled) ----
        float* f1buf = (float*)Hh;
        #pragma unroll
        for (int a = 0; a < 2; ++a) {
            const int n0 = (wv * 2 + a) * 16 + 4 * g;
            #pragma unroll
            for (int m = 0; m < 4; ++m) {
                const int row = 16 * m + r;
                float4 y;
                y.x = acc3[a][m][0];
                y.y = acc3[a][m][1];
                y.z = acc3[a][m][2];
                y.w = acc3[a][m][3];
                *(float4*)&f1buf[row * 128 + FX(row, n0)] = y;
            }
        }
        __syncthreads();

        // ---- segmented SUM pooling: thread = (col, 32-row half) ----
        {
            const int c = tid & 127, h = tid >> 7;
            const int r0p = h * 32;
            float accS = 0.f;
            int cur = -1;
            #pragma unroll
            for (int j = 0; j < 32; ++j) {
                const int rl = r0p + j;
                const int sg = (int)segid[rl];
                if (sg != cur) {
                    if ((unsigned)cur < (unsigned)NROW)
                        atomicAdd(&A.sumG[(size_t)cur * 128 + c], accS);
                    cur = sg; accS = 0.f;
                }
                accS += f1buf[rl * 128 + FX(rl, c)];
            }
            if ((unsigned)cur < (unsigned)NROW)
                atomicAdd(&A.sumG[(size_t)cur * 128 + c], accS);
        }
    } else {
        // ================= f1 paths 0..2 (32-row tiles) =================
        const int pb = blk - 8192;
        const int p = pb >> 8;
        const int row0 = (pb & 255) * 32;
        ush* Xh = (ush*)smem;                        // 32*32 = 2048 B
        ush* Xl = (ush*)(smem + 2048);
        ush* Hh = (ush*)(smem + 4096);               // 32*256 = 16384 B
        ush* Hl = (ush*)(smem + 20480);
        float* UT = (float*)(smem + 36864);          // 32 floats
        const float* Xg = A.X[p];
        const MlpPack P = A.P[p];
        float* f1_out = A.f1[p];
        float* ut_out = A.ut[p];
        if (tid < 32) UT[tid] = 0.f;
        for (int idx = tid; idx < 32 * 32; idx += 256) {
            const int row = idx >> 5, k = idx & 31;
            float v = 0.f;
            if (k < 16) v = Xg[(size_t)(row0 + row) * 16 + k];
            const uint32 uv = __float_as_uint(v);
            Xh[idx] = (ush)(uv >> 16);
            const float rest = v - __uint_as_float(uv & 0xFFFF0000u);
            Xl[idx] = (ush)(__float_as_uint(rest) >> 16);
        }
        __syncthreads();
        f32x4 acc3[2][2];
        mlp3_core32(P, 1, Xh, Xl, Hh, Hl, acc3);

        float utp[2] = {0.f, 0.f};
        #pragma unroll
        for (int a = 0; a < 2; ++a) {
            const int n0 = (wv * 2 + a) * 16 + 4 * g;
            const float4 av = *(const float4*)(attn + n0);
            #pragma unroll
            for (int m = 0; m < 2; ++m) {
                float4 y;
                y.x = acc3[a][m][0];
                y.y = acc3[a][m][1];
                y.z = acc3[a][m][2];
                y.w = acc3[a][m][3];
                *(float4*)&f1_out[(size_t)(row0 + 16 * m + r) * OUTc + n0] = y;
                utp[m] += y.x * av.x + y.y * av.y + y.z * av.z + y.w * av.w;
            }
        }
        #pragma unroll
        for (int m = 0; m < 2; ++m) {
            float v = utp[m];
            v += __shfl_xor(v, 16);
            v += __shfl_xor(v, 32);
            if (lane < 16) atomicAdd(&UT[16 * m + r], v);
        }
        __syncthreads();
        if (tid < 32) ut_out[row0 + tid] = UT[tid];
    }
}

// ---------------------------------------------------------------------------
// MLP4 path: 32 rows/block, finalizes x2 inline (cnt analytic).
// ---------------------------------------------------------------------------
__global__ __launch_bounds__(256, 3) void p3_kernel(
    MlpPack P, const float* __restrict__ attn,
    const float* __restrict__ sumG,
    const int* __restrict__ counts, const float* __restrict__ f1z,
    float* __restrict__ f1_out, float* __restrict__ ut_out)
{
    __shared__ ush Xh[32 * 128], Xl[32 * 128];
    __shared__ ush Hh[32 * 256], Hl[32 * 256];
    __shared__ float UT[32];
    const int tid = threadIdx.x;
    const int row0 = blockIdx.x * 32;
    if (tid < 32) UT[tid] = 0.f;
    for (int idx = tid; idx < 32 * 128; idx += 256) {
        const int row = idx >> 7, k = idx & 127;
        const size_t rid = (size_t)(row0 + row);
        const float na = (float)counts[rid];
        const float nz = 64.f - na;
        const float fz = f1z[k];
        const float v = (sumG[rid * 128 + k] + nz * fz)
                      / (na + nz * ((fz != 0.f) ? 1.f : 0.f));
        const uint32 uv = __float_as_uint(v);
        Xh[idx] = (ush)(uv >> 16);
        const float rest = v - __uint_as_float(uv & 0xFFFF0000u);
        Xl[idx] = (ush)(__float_as_uint(rest) >> 16);
    }
    __syncthreads();
    f32x4 acc3[2][2];
    mlp3_core32(P, 4, Xh, Xl, Hh, Hl, acc3);

    const int wv = tid >> 6, lane = tid & 63, r = lane & 15, g = lane >> 4;
    float utp[2] = {0.f, 0.f};
    #pragma unroll
    for (int a = 0; a < 2; ++a) {
        const int n0 = (wv * 2 + a) * 16 + 4 * g;
        const float4 av = *(const float4*)(attn + n0);
        #pragma unroll
        for (int m = 0; m < 2; ++m) {
            float4 y;
            y.x = acc3[a][m][0];
            y.y = acc3[a][m][1];
            y.z = acc3[a][m][2];
            y.w = acc3[a][m][3];
            *(float4*)&f1_out[(size_t)(row0 + 16 * m + r) * OUTc + n0] = y;
            utp[m] += y.x * av.x + y.y * av.y + y.z * av.z + y.w * av.w;
        }
    }
    #pragma unroll
    for (int m = 0; m < 2; ++m) {
        float v = utp[m];
        v += __shfl_xor(v, 16);
        v += __shfl_xor(v, 32);
        if (lane < 16) atomicAdd(&UT[16 * m + r], v);
    }
    __syncthreads();
    if (tid < 32) ut_out[row0 + tid] = UT[tid];
}

// ---------------------------------------------------------------------------
// combine with inline per-batch softmax: block = (b, 32-row chunk).
// ---------------------------------------------------------------------------
__global__ __launch_bounds__(256) void combine2_kernel(
    const float* __restrict__ uts,
    const float* __restrict__ pre_f1, const float* __restrict__ sub_f1,
    const float* __restrict__ self_f1, const float* __restrict__ ma_f2,
    float* __restrict__ out)
{
    __shared__ float sc[4 * NOPc];
    __shared__ float red[256];
    const int b = blockIdx.x >> 4, chunk = blockIdx.x & 15;
    const int t = threadIdx.x;
    const float* put = uts + 0 * NROW + (size_t)b * NOPc;
    const float* sut = uts + 1 * NROW + (size_t)b * NOPc;
    const float* eut = uts + 2 * NROW + (size_t)b * NOPc;
    const float* mut = uts + 3 * NROW + (size_t)b * NOPc;
    for (int i = t; i < NOPc; i += 256) {
        const float se = eut[i];
        const float s0 = put[i] + se, s1 = sut[i] + se, s2 = se + se, s3 = mut[i] + se;
        sc[0 * NOPc + i] = s0 > 0.f ? s0 : 0.2f * s0;
        sc[1 * NOPc + i] = s1 > 0.f ? s1 : 0.2f * s1;
        sc[2 * NOPc + i] = s2 > 0.f ? s2 : 0.2f * s2;
        sc[3 * NOPc + i] = s3 > 0.f ? s3 : 0.2f * s3;
    }
    __syncthreads();
    float mx = -INFINITY;
    for (int idx = t; idx < 4 * NOPc; idx += 256) mx = fmaxf(mx, sc[idx]);
    red[t] = mx;
    __syncthreads();
    for (int s = 128; s > 0; s >>= 1) { if (t < s) red[t] = fmaxf(red[t], red[t + s]); __syncthreads(); }
    mx = red[0];
    __syncthreads();
    float ps = 0.f;
    for (int idx = t; idx < 4 * NOPc; idx += 256) {
        const float e = expf(sc[idx] - mx);
        sc[idx] = e;
        ps += e;
    }
    red[t] = ps;
    __syncthreads();
    for (int s = 128; s > 0; s >>= 1) { if (t < s) red[t] += red[t + s]; __syncthreads(); }
    const float invZ = 1.f / red[0];

    const size_t base4 = (size_t)b * 16384 + (size_t)chunk * 1024;   // float4 units
    #pragma unroll
    for (int k = 0; k < 4; ++k) {
        const size_t e4 = base4 + k * 256 + t;
        const int i = (int)((e4 >> 5) & 511);
        const float a0 = sc[0 * NOPc + i] * invZ;
        const float a1 = sc[1 * NOPc + i] * invZ;
        const float a2 = sc[2 * NOPc + i] * invZ;
        const float a3 = sc[3 * NOPc + i] * invZ;
        const float4 vp = ((const float4*)pre_f1)[e4];
        const float4 vs = ((const float4*)sub_f1)[e4];
        const float4 ve = ((const float4*)self_f1)[e4];
        const float4 vm = ((const float4*)ma_f2)[e4];
        float4 o;
        o.x = 1.f / (1.f + expf(-(a0 * vp.x + a1 * vs.x + a2 * ve.x + a3 * vm.x)));
        o.y = 1.f / (1.f + expf(-(a0 * vp.y + a1 * vs.y + a2 * ve.y + a3 * vm.y)));
        o.z = 1.f / (1.f + expf(-(a0 * vp.z + a1 * vs.z + a2 * ve.z + a3 * vm.z)));
        o.w = 1.f / (1.f + expf(-(a0 * vp.w + a1 * vs.w + a2 * ve.w + a3 * vm.w)));
        ((float4*)out)[e4] = o;
    }
}

extern "C" void kernel_launch(void* const* d_in, const int* in_sizes, int n_in,
                              void* d_out, int out_size, void* d_ws, size_t ws_size,
                              hipStream_t stream) {
    const float* op      = (const float*)d_in[0];
    const float* ma      = (const float*)d_in[1];
    const float* eg      = (const float*)d_in[2];
    const int*   ma_adj  = (const int*)d_in[3];
    const int*   pre_adj = (const int*)d_in[4];
    const int*   sub_adj = (const int*)d_in[5];
    const int*   bidx    = (const int*)d_in[6];
    const float* attn    = (const float*)d_in[7];
    float* out = (float*)d_out;
    const float* Wraw[5][6];
    for (int m = 0; m < 5; ++m)
        for (int j = 0; j < 6; ++j)
            Wraw[m][j] = (const float*)d_in[8 + 6 * m + j];

    // ---- workspace layout ----
    float* wsf = (float*)d_ws;
    float* pre_agg = wsf;  wsf += (size_t)NROW * 16;
    float* sub_agg = wsf;  wsf += (size_t)NROW * 16;
    float* pre_f1  = wsf;  wsf += (size_t)NROW * OUTc;
    float* sub_f1  = wsf;  wsf += (size_t)NROW * OUTc;
    float* self_f1 = wsf;  wsf += (size_t)NROW * OUTc;
    float* ma_f2   = wsf;  wsf += (size_t)NROW * OUTc;
    float* uts     = wsf;  wsf += (size_t)4 * NROW;
    float* f1z     = wsf;  wsf += 128;
    float* sumG    = wsf;  wsf += (size_t)NROW * 128;
    int*   counts  = (int*)wsf;   wsf += NROW;
    int*   bases   = (int*)wsf;   wsf += NROW;
    int*   natot   = (int*)wsf;   wsf += 16;
    ush*   rowseg  = (ush*)wsf;   wsf += NEMAX / 2;
    ush*   Xq      = (ush*)wsf;   wsf += (size_t)NEMAX * 8;   // NEMAX rows * 16 ush
    ush*   packp   = (ush*)wsf;

    PrepArgs pa;
    MlpPack pk[5];
    for (int m = 0; m < 5; ++m) {
        const int kre[3] = { (m == 4 ? 128 : 16), 256, 256 };
        const int kbn[3] = { (m == 4 ? 4 : 1), 8, 8 };
        const int nbn[3] = { 16, 16, 8 };
        const ush* dh[3]; const ush* dl[3];
        for (int j = 0; j < 3; ++j) {
            const int id = m * 3 + j;
            pa.d[id].src = Wraw[m][2 * j];
            pa.d[id].kreal = kre[j];
            pa.d[id].kbn = kbn[j];
            pa.d[id].nbn = nbn[j];
            const int cnt = kbn[j] * nbn[j] * 512;
            pa.d[id].dh = packp; dh[j] = packp; packp += cnt;
            pa.d[id].dl = packp; dl[j] = packp; packp += cnt;
        }
        pk[m].w1h = dh[0]; pk[m].w1l = dl[0];
        pk[m].w2h = dh[1]; pk[m].w2l = dl[1];
        pk[m].w3h = dh[2]; pk[m].w3l = dl[2];
        pk[m].b1 = Wraw[m][1]; pk[m].b2 = Wraw[m][3]; pk[m].b3 = Wraw[m][5];
    }
    pa.op = op; pa.pre_adj = pre_adj; pa.sub_adj = sub_adj; pa.ma_adj = ma_adj;
    pa.bidx = bidx;
    pa.pre_agg = pre_agg; pa.sub_agg = sub_agg;
    pa.z_b1 = Wraw[0][1]; pa.z_w2 = Wraw[0][2]; pa.z_b2 = Wraw[0][3];
    pa.z_w3 = Wraw[0][4]; pa.z_b3 = Wraw[0][5];
    pa.f1z = f1z;
    pa.ma = ma; pa.eg = eg; pa.bases = bases;
    pa.Xq = Xq; pa.rowseg = rowseg; pa.sumG = sumG;

    EF1Args ea;
    ea.Xq = Xq; ea.rowseg = rowseg; ea.natot = natot; ea.P0 = pk[0];
    ea.sumG = sumG;
    ea.X[0] = pre_agg; ea.X[1] = sub_agg; ea.X[2] = op;
    ea.P[0] = pk[1];   ea.P[1] = pk[2];   ea.P[2] = pk[3];
    ea.f1[0] = pre_f1; ea.f1[1] = sub_f1; ea.f1[2] = self_f1;
    ea.ut[0] = uts + 0 * NROW;
    ea.ut[1] = uts + 1 * NROW;
    ea.ut[2] = uts + 2 * NROW;

    count_kernel<<<dim3(NROW / 4), 256, 0, stream>>>(ma_adj, bidx, counts);
    scan_kernel<<<1, 1024, 0, stream>>>(counts, bases, natot, Xq, rowseg);
    prep_kernel<<<dim3(960 + 1024 + 1 + NROW / 4), 256, 0, stream>>>(pa);
    edge_f1_kernel<<<dim3(8192 + 768), 256, 0, stream>>>(ea, attn);
    p3_kernel<<<dim3(256), 256, 0, stream>>>(pk[4], attn, sumG, counts, f1z,
                                             ma_f2, uts + 3 * NROW);
    combine2_kernel<<<dim3(NBb * 16), 256, 0, stream>>>(uts, pre_f1, sub_f1, self_f1, ma_f2, out);
}

// Round 13
// 147.723 us; speedup vs baseline: 1.2811x; 1.0831x over previous
//
#include <hip/hip_runtime.h>
#include <math.h>

#define NBb  16
#define NOPc 512
#define NMAc 64
#define HIDc 256
#define OUTc 128
#define NROW (NBb * NOPc)          // 8192 (b,i) rows
#define NEMAX (NROW * NMAc)        // 524288 max edges

// LDS swizzles: H row stride 512B is bank-aligned; fold 4 row bits into col.
#define HX(row, col) ((col) ^ (8 * ((row) & 15)))    // ush units (H buffers)
#define FX(row, col) ((col) ^ (4 * ((row) & 15)))    // f32 units (f1buf)

typedef unsigned int uint32;
typedef unsigned short ush;
typedef __attribute__((ext_vector_type(8))) short bf16x8;
typedef __attribute__((ext_vector_type(4))) float f32x4;

__device__ __forceinline__ ush f2bf(float v) {
    uint32 u = __float_as_uint(v);
    u += 0x7FFFu + ((u >> 16) & 1u);
    return (ush)(u >> 16);
}
__device__ __forceinline__ float bf2f(ush b) { return __uint_as_float(((uint32)b) << 16); }
__device__ __forceinline__ float eluf(float x) { return x > 0.f ? x : expm1f(x); }
__device__ __forceinline__ float eluf_fast(float x) { return x > 0.f ? x : __expf(x) - 1.f; }
// pack two floats' truncated bf16 into one u32: low = bf16(a), high = bf16(b)
__device__ __forceinline__ uint32 pkbf(float a, float b) {
    return __builtin_amdgcn_perm(__float_as_uint(b), __float_as_uint(a), 0x07060302u);
}
__device__ __forceinline__ uint32 pkbf_rne(float a, float b) {
    return (uint32)f2bf(a) | ((uint32)f2bf(b) << 16);
}
// truncation hi/lo split of 2 floats (residual captured exactly by lo plane)
__device__ __forceinline__ void split2(float a, float b, uint32& hp, uint32& lp) {
    const uint32 ua = __float_as_uint(a), ub = __float_as_uint(b);
    hp = __builtin_amdgcn_perm(ub, ua, 0x07060302u);
    const float ra = a - __uint_as_float(ua & 0xFFFF0000u);
    const float rb = b - __uint_as_float(ub & 0xFFFF0000u);
    lp = __builtin_amdgcn_perm(__float_as_uint(rb), __float_as_uint(ra), 0x07060302u);
}
// pack two 0/1 ints as bf16 pair (1.0f -> 0x3F80)
__device__ __forceinline__ uint32 pkadj(int a, int b) {
    return (a ? 0x3F80u : 0u) | (b ? 0x3F800000u : 0u);
}

#define MFMA(A, B, C) __builtin_amdgcn_mfma_f32_16x16x32_bf16((A), (B), (C), 0, 0, 0)

// pack[((kb*nbn + nb)*64 + lane)*8 + e] = W[kb*32 + 8*(lane>>4) + e][nb*16 + (lane&15)]
struct MlpPack {
    const ush *w1h, *w1l, *w2h, *w2l, *w3h, *w3l;
    const float *b1, *b2, *b3;
};

// ---------------------------------------------------------------------------
// Hi/lo (bf16x3) 3-layer core, 32-row tile. Bias pre-loaded into MFMA C-in;
// acc3 returned WITH bias.
// ---------------------------------------------------------------------------
__device__ __forceinline__ void mlp3_core32(
    const MlpPack& P, const int KB1,
    const ush* Xh, const ush* Xl, ush* Hh, ush* Hl, f32x4 acc3[2][2])
{
    const int tid = threadIdx.x;
    const int wv = tid >> 6, lane = tid & 63, r = lane & 15, g = lane >> 4;
    const int KX = KB1 * 32;

    // layer 1: KX -> 256
    {
        f32x4 acc[4][2];
        #pragma unroll
        for (int a = 0; a < 4; ++a) {
            const float4 bv = *(const float4*)(P.b1 + (wv * 4 + a) * 16 + 4 * g);
            #pragma unroll
            for (int m = 0; m < 2; ++m) acc[a][m] = f32x4{bv.x, bv.y, bv.z, bv.w};
        }
        #pragma unroll 1
        for (int kb = 0; kb < KB1; ++kb) {
            bf16x8 wh[4], wl[4];
            #pragma unroll
            for (int a = 0; a < 4; ++a) {
                const size_t o = ((size_t)(kb * 16 + (wv * 4 + a)) * 64 + lane) * 8;
                wh[a] = *(const bf16x8*)(P.w1h + o);
                wl[a] = *(const bf16x8*)(P.w1l + o);
            }
            #pragma unroll
            for (int m = 0; m < 2; ++m) {
                const int row = 16 * m + r;
                const int ki = kb * 32 + 8 * g;
                bf16x8 xh = *(const bf16x8*)(Xh + row * KX + ki);
                bf16x8 xl = *(const bf16x8*)(Xl + row * KX + ki);
                #pragma unroll
                for (int a = 0; a < 4; ++a) {
                    acc[a][m] = MFMA(wh[a], xh, acc[a][m]);
                    acc[a][m] = MFMA(wh[a], xl, acc[a][m]);
                    acc[a][m] = MFMA(wl[a], xh, acc[a][m]);
                }
            }
        }
        #pragma unroll
        for (int a = 0; a < 4; ++a) {
            const int n0 = (wv * 4 + a) * 16 + 4 * g;
            #pragma unroll
            for (int m = 0; m < 2; ++m) {
                const int row = 16 * m + r;
                const float y0 = eluf_fast(acc[a][m][0]);
                const float y1 = eluf_fast(acc[a][m][1]);
                const float y2 = eluf_fast(acc[a][m][2]);
                const float y3 = eluf_fast(acc[a][m][3]);
                uint2 uh, ul;
                split2(y0, y1, uh.x, ul.x);
                split2(y2, y3, uh.y, ul.y);
                const int idx = row * 256 + HX(row, n0);
                *(uint2*)(Hh + idx) = uh;
                *(uint2*)(Hl + idx) = ul;
            }
        }
    }
    __syncthreads();

    // layer 2: 256 -> 256 (in place)
    {
        f32x4 acc[4][2];
        #pragma unroll
        for (int a = 0; a < 4; ++a) {
            const float4 bv = *(const float4*)(P.b2 + (wv * 4 + a) * 16 + 4 * g);
            #pragma unroll
            for (int m = 0; m < 2; ++m) acc[a][m] = f32x4{bv.x, bv.y, bv.z, bv.w};
        }
        #pragma unroll 1
        for (int kb = 0; kb < 8; ++kb) {
            bf16x8 wh[4], wl[4];
            #pragma unroll
            for (int a = 0; a < 4; ++a) {
                const size_t o = ((size_t)(kb * 16 + (wv * 4 + a)) * 64 + lane) * 8;
                wh[a] = *(const bf16x8*)(P.w2h + o);
                wl[a] = *(const bf16x8*)(P.w2l + o);
            }
            #pragma unroll
            for (int m = 0; m < 2; ++m) {
                const int row = 16 * m + r;
                const int k0 = kb * 32 + 8 * g;
                const int idx = row * 256 + HX(row, k0);
                bf16x8 hh = *(const bf16x8*)(Hh + idx);
                bf16x8 hl = *(const bf16x8*)(Hl + idx);
                #pragma unroll
                for (int a = 0; a < 4; ++a) {
                    acc[a][m] = MFMA(wh[a], hh, acc[a][m]);
                    acc[a][m] = MFMA(wh[a], hl, acc[a][m]);
                    acc[a][m] = MFMA(wl[a], hh, acc[a][m]);
                }
            }
        }
        __syncthreads();
        #pragma unroll
        for (int a = 0; a < 4; ++a) {
            const int n0 = (wv * 4 + a) * 16 + 4 * g;
            #pragma unroll
            for (int m = 0; m < 2; ++m) {
                const int row = 16 * m + r;
                const float y0 = eluf_fast(acc[a][m][0]);
                const float y1 = eluf_fast(acc[a][m][1]);
                const float y2 = eluf_fast(acc[a][m][2]);
                const float y3 = eluf_fast(acc[a][m][3]);
                uint2 uh, ul;
                split2(y0, y1, uh.x, ul.x);
                split2(y2, y3, uh.y, ul.y);
                const int idx = row * 256 + HX(row, n0);
                *(uint2*)(Hh + idx) = uh;
                *(uint2*)(Hl + idx) = ul;
            }
        }
    }
    __syncthreads();

    // layer 3: 256 -> 128 (acc3 includes bias)
    {
        #pragma unroll
        for (int a = 0; a < 2; ++a) {
            const float4 bv = *(const float4*)(P.b3 + (wv * 2 + a) * 16 + 4 * g);
            #pragma unroll
            for (int m = 0; m < 2; ++m) acc3[a][m] = f32x4{bv.x, bv.y, bv.z, bv.w};
        }
        #pragma unroll 1
        for (int kb = 0; kb < 8; ++kb) {
            bf16x8 wh[2], wl[2];
            #pragma unroll
            for (int a = 0; a < 2; ++a) {
                const size_t o = ((size_t)(kb * 8 + (wv * 2 + a)) * 64 + lane) * 8;
                wh[a] = *(const bf16x8*)(P.w3h + o);
                wl[a] = *(const bf16x8*)(P.w3l + o);
            }
            #pragma unroll
            for (int m = 0; m < 2; ++m) {
                const int row = 16 * m + r;
                const int k0 = kb * 32 + 8 * g;
                const int idx = row * 256 + HX(row, k0);
                bf16x8 hh = *(const bf16x8*)(Hh + idx);
                bf16x8 hl = *(const bf16x8*)(Hl + idx);
                #pragma unroll
                for (int a = 0; a < 2; ++a) {
                    acc3[a][m] = MFMA(wh[a], hh, acc3[a][m]);
                    acc3[a][m] = MFMA(wh[a], hl, acc3[a][m]);
                    acc3[a][m] = MFMA(wl[a], hh, acc3[a][m]);
                }
            }
        }
    }
}

// ---------------------------------------------------------------------------
// count: ma-edge count per (b,i). 4 rids per block (one per wave).
// ---------------------------------------------------------------------------
__global__ __launch_bounds__(256) void count_kernel(const int* __restrict__ ma_adj,
                                                    const int* __restrict__ bidx,
                                                    int* __restrict__ counts)
{
    const int tid = threadIdx.x;
    const int rid = blockIdx.x * 4 + (tid >> 6);
    const int lane = tid & 63;
    const int b = rid >> 9, i = rid & 511;
    const int bi = bidx[b];
    const int active = (ma_adj[((size_t)bi * NOPc + i) * NMAc + lane] != 0) ? 1 : 0;
    const unsigned long long mk = __ballot(active);
    if (lane == 0) counts[rid] = (int)__popcll(mk);
}

// ---------------------------------------------------------------------------
// scan: exclusive prefix over counts[8192] -> bases, natot; zero/sentinel pad.
// ---------------------------------------------------------------------------
__global__ __launch_bounds__(1024) void scan_kernel(const int* __restrict__ counts,
                                                    int* __restrict__ bases,
                                                    int* __restrict__ natot,
                                                    ush* __restrict__ Xq,
                                                    ush* __restrict__ rowseg)
{
    __shared__ int tot[1024];
    const int t = threadIdx.x;
    int loc[8];
    int s = 0;
    #pragma unroll
    for (int k = 0; k < 8; ++k) { loc[k] = s; s += counts[t * 8 + k]; }
    tot[t] = s;
    __syncthreads();
    for (int off = 1; off < 1024; off <<= 1) {
        const int v = (t >= off) ? tot[t - off] : 0;
        __syncthreads();
        tot[t] += v;
        __syncthreads();
    }
    const int base = tot[t] - s;   // exclusive
    #pragma unroll
    for (int k = 0; k < 8; ++k) bases[t * 8 + k] = base + loc[k];
    const int NA = tot[1023];
    if (t == 0) *natot = NA;
    __syncthreads();
    const int NApad = (NA + 63) & ~63;
    for (int idx = NA * 16 + t; idx < NApad * 16; idx += 1024) Xq[idx] = 0;
    for (int idx = NA + t; idx < NApad; idx += 1024) rowseg[idx] = (ush)0xFFFFu;
}

// ---------------------------------------------------------------------------
// prep: pack [0,960) + MFMA-agg [960,1088) + f1z (1088) + scatter [1089,3137).
// ---------------------------------------------------------------------------
struct PackDesc { const float* src; ush* dh; ush* dl; int kreal; int kbn; int nbn; };
struct PrepArgs {
    PackDesc d[15];
    const float* op; const int* pre_adj; const int* sub_adj; const int* ma_adj;
    const int* bidx;
    float* pre_agg; float* sub_agg;
    const float *z_b1, *z_w2, *z_b2, *z_w3, *z_b3;
    float* f1z;
    const float* ma; const float* eg; const int* bases;
    ush* Xq; ush* rowseg; float* sumG;
};

__global__ __launch_bounds__(256) void prep_kernel(PrepArgs A)
{
    __shared__ float shmem[8192];      // 32 KB
    const int blk = blockIdx.x;
    const int t = threadIdx.x;
    if (blk < 960) {
        // ---- weight pack ----
        const PackDesc d = A.d[blk >> 6];
        const int sub = blk & 63;
        const int total = d.kbn * d.nbn * 512;
        const int N = d.nbn * 16;
        for (int idx = sub * 256 + t; idx < total; idx += 64 * 256) {
            const int e = idx & 7;
            const int l = (idx >> 3) & 63;
            const int t2 = idx >> 9;
            const int nb = t2 % d.nbn;
            const int kb = t2 / d.nbn;
            const int k = kb * 32 + ((l >> 4) << 3) + e;
            const int n = nb * 16 + (l & 15);
            const float v = (k < d.kreal) ? d.src[(size_t)k * N + n] : 0.f;
            const ush hi = f2bf(v);
            d.dh[idx] = hi;
            d.dl[idx] = f2bf(v - bf2f(hi));
        }
    } else if (blk < 1088) {
        // ---- MFMA agg: block = (b, 64-i group). op[b] staged as hi/lo
        //      bf16 fragments in LDS; adj converted to 0/1 bf16 on the fly.
        //      pre_agg[i,:] = sum_j adj[i,j]*op[j,:]  (exact adj, hi/lo op).
        const int e = blk - 960;
        const int b = e >> 3;
        const int i0 = (e & 7) * 64;
        const int bi = A.bidx[b];
        ush* opH = (ush*)shmem;              // [16 kb][64 lane][8 e]
        ush* opL = opH + 8192;
        // stage op[b] (512 x 16 f32) into fragment order, hi/lo
        for (int idx = t; idx < 8192; idx += 256) {
            const int j = idx >> 4, dd = idx & 15;
            const float v = A.op[(size_t)b * 8192 + idx];
            const int kb = j >> 5, gg = (j >> 3) & 3, ee = j & 7;
            const int di = ((kb * 64 + gg * 16 + dd) << 3) + ee;
            const uint32 uv = __float_as_uint(v);
            opH[di] = (ush)(uv >> 16);
            const float rest = v - __uint_as_float(uv & 0xFFFF0000u);
            opL[di] = (ush)(__float_as_uint(rest) >> 16);
        }
        __syncthreads();
        const int wv = t >> 6, lane = t & 63, r = lane & 15, g = lane >> 4;
        const int i = i0 + wv * 16 + r;
        const int4* pr4 = (const int4*)(A.pre_adj + ((size_t)bi * NOPc + i) * NOPc);
        const int4* sr4 = (const int4*)(A.sub_adj + ((size_t)bi * NOPc + i) * NOPc);
        f32x4 accP = {0.f, 0.f, 0.f, 0.f}, accS = {0.f, 0.f, 0.f, 0.f};
        #pragma unroll 2
        for (int kb = 0; kb < 16; ++kb) {
            const int jo = kb * 8 + 2 * g;     // int4 index of j = kb*32 + 8g
            const int4 p0 = pr4[jo], p1 = pr4[jo + 1];
            const int4 s0 = sr4[jo], s1 = sr4[jo + 1];
            bf16x8 ap, as;
            {
                uint32 u0 = pkadj(p0.x, p0.y), u1 = pkadj(p0.z, p0.w);
                uint32 u2 = pkadj(p1.x, p1.y), u3 = pkadj(p1.z, p1.w);
                uint32* pa = (uint32*)&ap;
                pa[0] = u0; pa[1] = u1; pa[2] = u2; pa[3] = u3;
            }
            {
                uint32 u0 = pkadj(s0.x, s0.y), u1 = pkadj(s0.z, s0.w);
                uint32 u2 = pkadj(s1.x, s1.y), u3 = pkadj(s1.z, s1.w);
                uint32* pa = (uint32*)&as;
                pa[0] = u0; pa[1] = u1; pa[2] = u2; pa[3] = u3;
            }
            const bf16x8 oh = *(const bf16x8*)(opH + ((kb * 64 + lane) << 3));
            const bf16x8 ol = *(const bf16x8*)(opL + ((kb * 64 + lane) << 3));
            accP = MFMA(oh, ap, accP);
            accP = MFMA(ol, ap, accP);
            accS = MFMA(oh, as, accS);
            accS = MFMA(ol, as, accS);
        }
        // D: value for d = 4g+q, row i (r). float4 store.
        float4 vp, vs;
        vp.x = accP[0]; vp.y = accP[1]; vp.z = accP[2]; vp.w = accP[3];
        vs.x = accS[0]; vs.y = accS[1]; vs.z = accS[2]; vs.w = accS[3];
        *(float4*)&A.pre_agg[((size_t)b * NOPc + i) * 16 + 4 * g] = vp;
        *(float4*)&A.sub_agg[((size_t)b * NOPc + i) * 16 + 4 * g] = vs;
    } else if (blk == 1088) {
        // ---- f1z = MLP0(0) in raw f32 ----
        shmem[t] = eluf(A.z_b1[t]);
        __syncthreads();
        float acc = A.z_b2[t];
        for (int k = 0; k < 256; ++k) acc += shmem[k] * A.z_w2[(size_t)k * 256 + t];
        __syncthreads();
        shmem[256 + t] = eluf(acc);
        __syncthreads();
        if (t < 128) {
            float a = A.z_b3[t];
            for (int k = 0; k < 256; ++k) a += shmem[256 + k] * A.z_w3[(size_t)k * 128 + t];
            A.f1z[t] = a;
        }
    } else {
        // ---- scatter: dense bf16 edge rows + rowseg; zero sumG ----
        const int rid = (blk - 1089) * 4 + (t >> 6);
        const int lane = t & 63;
        const int b = rid >> 9, i = rid & 511;
        const int bi = A.bidx[b];
        const int act = (A.ma_adj[((size_t)bi * NOPc + i) * NMAc + lane] != 0) ? 1 : 0;
        const unsigned long long mk = __ballot(act);
        if (act) {
            const int pos = A.bases[rid] + (int)__popcll(mk & ((1ull << lane) - 1ull));
            const float4* mp = (const float4*)(A.ma + ((size_t)b * NMAc + lane) * 8);
            const float4* ep = (const float4*)(A.eg + (((size_t)b * NOPc + i) * NMAc + lane) * 8);
            const float4 m0 = mp[0], m1 = mp[1], e0 = ep[0], e1 = ep[1];
            uint4 u0, u1;
            u0.x = pkbf_rne(m0.x, m0.y); u0.y = pkbf_rne(m0.z, m0.w);
            u0.z = pkbf_rne(m1.x, m1.y); u0.w = pkbf_rne(m1.z, m1.w);
            u1.x = pkbf_rne(e0.x, e0.y); u1.y = pkbf_rne(e0.z, e0.w);
            u1.z = pkbf_rne(e1.x, e1.y); u1.w = pkbf_rne(e1.z, e1.w);
            uint4* dst = (uint4*)(A.Xq + (size_t)pos * 16);
            dst[0] = u0;
            dst[1] = u1;
            A.rowseg[pos] = (ush)rid;
        }
        A.sumG[(size_t)rid * 128 + lane] = 0.f;
        A.sumG[(size_t)rid * 128 + 64 + lane] = 0.f;
    }
}

// ---------------------------------------------------------------------------
// Fused kernel: blocks [0,8192) = edge MLP0 tiles; [8192, 8960) = f1 paths.
// ---------------------------------------------------------------------------
struct EF1Args {
    const ush* Xq; const ush* rowseg; const int* natot; MlpPack P0;
    float* sumG;
    const float* X[3]; MlpPack P[3]; float* f1[3]; float* ut[3];
};

__global__ __launch_bounds__(256, 4) void edge_f1_kernel(EF1Args A, const float* __restrict__ attn)
{
    __shared__ unsigned char smem[36992];
    const int blk = blockIdx.x;
    const int tid = threadIdx.x;
    const int wv = tid >> 6, lane = tid & 63, r = lane & 15, g = lane >> 4;

    if (blk < 8192) {
        // ================= edge path =================
        const int NA = *A.natot;
        const int tile = blk;
        if (tile * 64 >= NA) return;
        ush* Hh = (ush*)smem;                       // 64*256 ush = 32768 B
        ush* segid = (ush*)(smem + 32768);          // 64 ush
        const MlpPack& P = A.P0;
        if (tid < 64) segid[tid] = A.rowseg[(size_t)tile * 64 + tid];

        // ---- layer 1: 32 -> 256, X direct from dense global queue ----
        {
            f32x4 acc[4][4];
            #pragma unroll
            for (int a = 0; a < 4; ++a) {
                const float4 bv = *(const float4*)(P.b1 + (wv * 4 + a) * 16 + 4 * g);
                #pragma unroll
                for (int m = 0; m < 4; ++m) acc[a][m] = f32x4{bv.x, bv.y, bv.z, bv.w};
            }
            bf16x8 wh[4];
            #pragma unroll
            for (int a = 0; a < 4; ++a)
                wh[a] = *(const bf16x8*)(P.w1h + ((size_t)(wv * 4 + a) * 64 + lane) * 8);
            #pragma unroll
            for (int m = 0; m < 4; ++m) {
                const int gr = tile * 64 + 16 * m + r;
                bf16x8 xh = {0, 0, 0, 0, 0, 0, 0, 0};
                if (g < 2) xh = *(const bf16x8*)(A.Xq + (size_t)gr * 16 + 8 * g);
                #pragma unroll
                for (int a = 0; a < 4; ++a) acc[a][m] = MFMA(wh[a], xh, acc[a][m]);
            }
            #pragma unroll
            for (int a = 0; a < 4; ++a) {
                const int n0 = (wv * 4 + a) * 16 + 4 * g;
                #pragma unroll
                for (int m = 0; m < 4; ++m) {
                    const int row = 16 * m + r;
                    const float y0 = eluf_fast(acc[a][m][0]);
                    const float y1 = eluf_fast(acc[a][m][1]);
                    const float y2 = eluf_fast(acc[a][m][2]);
                    const float y3 = eluf_fast(acc[a][m][3]);
                    uint2 u; u.x = pkbf(y0, y1); u.y = pkbf(y2, y3);
                    *(uint2*)(Hh + row * 256 + HX(row, n0)) = u;
                }
            }
        }
        __syncthreads();

        // ---- layer 2: 256 -> 256 (in place) ----
        {
            f32x4 acc[4][4];
            #pragma unroll
            for (int a = 0; a < 4; ++a) {
                const float4 bv = *(const float4*)(P.b2 + (wv * 4 + a) * 16 + 4 * g);
                #pragma unroll
                for (int m = 0; m < 4; ++m) acc[a][m] = f32x4{bv.x, bv.y, bv.z, bv.w};
            }
            #pragma unroll 1
            for (int kb = 0; kb < 8; ++kb) {
                bf16x8 wh[4];
                #pragma unroll
                for (int a = 0; a < 4; ++a)
                    wh[a] = *(const bf16x8*)(P.w2h + ((size_t)(kb * 16 + (wv * 4 + a)) * 64 + lane) * 8);
                #pragma unroll
                for (int m = 0; m < 4; ++m) {
                    const int row = 16 * m + r;
                    const int k0 = kb * 32 + 8 * g;
                    bf16x8 hh = *(const bf16x8*)(Hh + row * 256 + HX(row, k0));
                    #pragma unroll
                    for (int a = 0; a < 4; ++a) acc[a][m] = MFMA(wh[a], hh, acc[a][m]);
                }
            }
            __syncthreads();
            #pragma unroll
            for (int a = 0; a < 4; ++a) {
                const int n0 = (wv * 4 + a) * 16 + 4 * g;
                #pragma unroll
                for (int m = 0; m < 4; ++m) {
                    const int row = 16 * m + r;
                    const float y0 = eluf_fast(acc[a][m][0]);
                    const float y1 = eluf_fast(acc[a][m][1]);
                    const float y2 = eluf_fast(acc[a][m][2]);
                    const float y3 = eluf_fast(acc[a][m][3]);
                    uint2 u; u.x = pkbf(y0, y1); u.y = pkbf(y2, y3);
                    *(uint2*)(Hh + row * 256 + HX(row, n0)) = u;
                }
            }
        }
        __syncthreads();

        // ---- layer 3: 256 -> 128 (acc includes bias) ----
        f32x4 acc3[2][4];
        #pragma unroll
        for (int a = 0; a < 2; ++a) {
            const float4 bv = *(const float4*)(P.b3 + (wv * 2 + a) * 16 + 4 * g);
            #pragma unroll
            for (int m = 0; m < 4; ++m) acc3[a][m] = f32x4{bv.x, bv.y, bv.z, bv.w};
        }
        #pragma unroll 1
        for (int kb = 0; kb < 8; ++kb) {
            bf16x8 wh[2];
            #pragma unroll
            for (int a = 0; a < 2; ++a)
                wh[a] = *(const bf16x8*)(P.w3h + ((size_t)(kb * 8 + (wv * 2 + a)) * 64 + lane) * 8);
            #pragma unroll
            for (int m = 0; m < 4; ++m) {
                const int row = 16 * m + r;
                const int k0 = kb * 32 + 8 * g;
                bf16x8 hh = *(const bf16x8*)(Hh + row * 256 + HX(row, k0));
                #pragma unroll
                for (int a = 0; a < 2; ++a) acc3[a][m] = MFMA(wh[a], hh, acc3[a][m]);
            }
        }
        __syncthreads();            // all Hh reads complete before aliasing as f1buf

        // ---- write y rows to LDS f1buf (f32, XOR-swizzled) ----
        float* f1buf = (float*)Hh;
        #pragma unroll
        for (int a = 0; a < 2; ++a) {
            const int n0 = (wv * 2 + a) * 16 + 4 * g;
            #pragma unroll
            for (int m = 0; m < 4; ++m) {
                const int row = 16 * m + r;
                float4 y;
                y.x = acc3[a][m][0];
                y.y = acc3[a][m][1];
                y.z = acc3[a][m][2];
                y.w = acc3[a][m][3];
                *(float4*)&f1buf[row * 128 + FX(row, n0)] = y;
            }
        }
        __syncthreads();

        // ---- segmented SUM pooling: thread = (col, 32-row half) ----
        {
            const int c = tid & 127, h = tid >> 7;
            const int r0p = h * 32;
            float accS = 0.f;
            int cur = -1;
            #pragma unroll
            for (int j = 0; j < 32; ++j) {
                const int rl = r0p + j;
                const int sg = (int)segid[rl];
                if (sg != cur) {
                    if ((unsigned)cur < (unsigned)NROW)
                        atomicAdd(&A.sumG[(size_t)cur * 128 + c], accS);
                    cur = sg; accS = 0.f;
                }
                accS += f1buf[rl * 128 + FX(rl, c)];
            }
            if ((unsigned)cur < (unsigned)NROW)
                atomicAdd(&A.sumG[(size_t)cur * 128 + c], accS);
        }
    } else {
        // ================= f1 paths 0..2 (32-row tiles) =================
        const int pb = blk - 8192;
        const int p = pb >> 8;
        const int row0 = (pb & 255) * 32;
        ush* Xh = (ush*)smem;                        // 32*32 = 2048 B
        ush* Xl = (ush*)(smem + 2048);
        ush* Hh = (ush*)(smem + 4096);               // 32*256 = 16384 B
        ush* Hl = (ush*)(smem + 20480);
        float* UT = (float*)(smem + 36864);          // 32 floats
        const float* Xg = A.X[p];
        const MlpPack P = A.P[p];
        float* f1_out = A.f1[p];
        float* ut_out = A.ut[p];
        if (tid < 32) UT[tid] = 0.f;
        for (int idx = tid; idx < 32 * 32; idx += 256) {
            const int row = idx >> 5, k = idx & 31;
            float v = 0.f;
            if (k < 16) v = Xg[(size_t)(row0 + row) * 16 + k];
            const uint32 uv = __float_as_uint(v);
            Xh[idx] = (ush)(uv >> 16);
            const float rest = v - __uint_as_float(uv & 0xFFFF0000u);
            Xl[idx] = (ush)(__float_as_uint(rest) >> 16);
        }
        __syncthreads();
        f32x4 acc3[2][2];
        mlp3_core32(P, 1, Xh, Xl, Hh, Hl, acc3);

        float utp[2] = {0.f, 0.f};
        #pragma unroll
        for (int a = 0; a < 2; ++a) {
            const int n0 = (wv * 2 + a) * 16 + 4 * g;
            const float4 av = *(const float4*)(attn + n0);
            #pragma unroll
            for (int m = 0; m < 2; ++m) {
                float4 y;
                y.x = acc3[a][m][0];
                y.y = acc3[a][m][1];
                y.z = acc3[a][m][2];
                y.w = acc3[a][m][3];
                *(float4*)&f1_out[(size_t)(row0 + 16 * m + r) * OUTc + n0] = y;
                utp[m] += y.x * av.x + y.y * av.y + y.z * av.z + y.w * av.w;
            }
        }
        #pragma unroll
        for (int m = 0; m < 2; ++m) {
            float v = utp[m];
            v += __shfl_xor(v, 16);
            v += __shfl_xor(v, 32);
            if (lane < 16) atomicAdd(&UT[16 * m + r], v);
        }
        __syncthreads();
        if (tid < 32) ut_out[row0 + tid] = UT[tid];
    }
}

// ---------------------------------------------------------------------------
// MLP4 path: 32 rows/block, finalizes x2 inline (cnt analytic).
// ---------------------------------------------------------------------------
__global__ __launch_bounds__(256, 3) void p3_kernel(
    MlpPack P, const float* __restrict__ attn,
    const float* __restrict__ sumG,
    const int* __restrict__ counts, const float* __restrict__ f1z,
    float* __restrict__ f1_out, float* __restrict__ ut_out)
{
    __shared__ ush Xh[32 * 128], Xl[32 * 128];
    __shared__ ush Hh[32 * 256], Hl[32 * 256];
    __shared__ float UT[32];
    const int tid = threadIdx.x;
    const int row0 = blockIdx.x * 32;
    if (tid < 32) UT[tid] = 0.f;
    for (int idx = tid; idx < 32 * 128; idx += 256) {
        const int row = idx >> 7, k = idx & 127;
        const size_t rid = (size_t)(row0 + row);
        const float na = (float)counts[rid];
        const float nz = 64.f - na;
        const float fz = f1z[k];
        const float v = (sumG[rid * 128 + k] + nz * fz)
                      / (na + nz * ((fz != 0.f) ? 1.f : 0.f));
        const uint32 uv = __float_as_uint(v);
        Xh[idx] = (ush)(uv >> 16);
        const float rest = v - __uint_as_float(uv & 0xFFFF0000u);
        Xl[idx] = (ush)(__float_as_uint(rest) >> 16);
    }
    __syncthreads();
    f32x4 acc3[2][2];
    mlp3_core32(P, 4, Xh, Xl, Hh, Hl, acc3);

    const int wv = tid >> 6, lane = tid & 63, r = lane & 15, g = lane >> 4;
    float utp[2] = {0.f, 0.f};
    #pragma unroll
    for (int a = 0; a < 2; ++a) {
        const int n0 = (wv * 2 + a) * 16 + 4 * g;
        const float4 av = *(const float4*)(attn + n0);
        #pragma unroll
        for (int m = 0; m < 2; ++m) {
            float4 y;
            y.x = acc3[a][m][0];
            y.y = acc3[a][m][1];
            y.z = acc3[a][m][2];
            y.w = acc3[a][m][3];
            *(float4*)&f1_out[(size_t)(row0 + 16 * m + r) * OUTc + n0] = y;
            utp[m] += y.x * av.x + y.y * av.y + y.z * av.z + y.w * av.w;
        }
    }
    #pragma unroll
    for (int m = 0; m < 2; ++m) {
        float v = utp[m];
        v += __shfl_xor(v, 16);
        v += __shfl_xor(v, 32);
        if (lane < 16) atomicAdd(&UT[16 * m + r], v);
    }
    __syncthreads();
    if (tid < 32) ut_out[row0 + tid] = UT[tid];
}

// ---------------------------------------------------------------------------
// combine with inline per-batch softmax: block = (b, 32-row chunk).
// ---------------------------------------------------------------------------
__global__ __launch_bounds__(256) void combine2_kernel(
    const float* __restrict__ uts,
    const float* __restrict__ pre_f1, const float* __restrict__ sub_f1,
    const float* __restrict__ self_f1, const float* __restrict__ ma_f2,
    float* __restrict__ out)
{
    __shared__ float sc[4 * NOPc];
    __shared__ float red[256];
    const int b = blockIdx.x >> 4, chunk = blockIdx.x & 15;
    const int t = threadIdx.x;
    const float* put = uts + 0 * NROW + (size_t)b * NOPc;
    const float* sut = uts + 1 * NROW + (size_t)b * NOPc;
    const float* eut = uts + 2 * NROW + (size_t)b * NOPc;
    const float* mut = uts + 3 * NROW + (size_t)b * NOPc;
    for (int i = t; i < NOPc; i += 256) {
        const float se = eut[i];
        const float s0 = put[i] + se, s1 = sut[i] + se, s2 = se + se, s3 = mut[i] + se;
        sc[0 * NOPc + i] = s0 > 0.f ? s0 : 0.2f * s0;
        sc[1 * NOPc + i] = s1 > 0.f ? s1 : 0.2f * s1;
        sc[2 * NOPc + i] = s2 > 0.f ? s2 : 0.2f * s2;
        sc[3 * NOPc + i] = s3 > 0.f ? s3 : 0.2f * s3;
    }
    __syncthreads();
    float mx = -INFINITY;
    for (int idx = t; idx < 4 * NOPc; idx += 256) mx = fmaxf(mx, sc[idx]);
    red[t] = mx;
    __syncthreads();
    for (int s = 128; s > 0; s >>= 1) { if (t < s) red[t] = fmaxf(red[t], red[t + s]); __syncthreads(); }
    mx = red[0];
    __syncthreads();
    float ps = 0.f;
    for (int idx = t; idx < 4 * NOPc; idx += 256) {
        const float e = expf(sc[idx] - mx);
        sc[idx] = e;
        ps += e;
    }
    red[t] = ps;
    __syncthreads();
    for (int s = 128; s > 0; s >>= 1) { if (t < s) red[t] += red[t + s]; __syncthreads(); }
    const float invZ = 1.f / red[0];

    const size_t base4 = (size_t)b * 16384 + (size_t)chunk * 1024;   // float4 units
    #pragma unroll
    for (int k = 0; k < 4; ++k) {
        const size_t e4 = base4 + k * 256 + t;
        const int i = (int)((e4 >> 5) & 511);
        const float a0 = sc[0 * NOPc + i] * invZ;
        const float a1 = sc[1 * NOPc + i] * invZ;
        const float a2 = sc[2 * NOPc + i] * invZ;
        const float a3 = sc[3 * NOPc + i] * invZ;
        const float4 vp = ((const float4*)pre_f1)[e4];
        const float4 vs = ((const float4*)sub_f1)[e4];
        const float4 ve = ((const float4*)self_f1)[e4];
        const float4 vm = ((const float4*)ma_f2)[e4];
        float4 o;
        o.x = 1.f / (1.f + expf(-(a0 * vp.x + a1 * vs.x + a2 * ve.x + a3 * vm.x)));
        o.y = 1.f / (1.f + expf(-(a0 * vp.y + a1 * vs.y + a2 * ve.y + a3 * vm.y)));
        o.z = 1.f / (1.f + expf(-(a0 * vp.z + a1 * vs.z + a2 * ve.z + a3 * vm.z)));
        o.w = 1.f / (1.f + expf(-(a0 * vp.w + a1 * vs.w + a2 * ve.w + a3 * vm.w)));
        ((float4*)out)[e4] = o;
    }
}

extern "C" void kernel_launch(void* const* d_in, const int* in_sizes, int n_in,
                              void* d_out, int out_size, void* d_ws, size_t ws_size,
                              hipStream_t stream) {
    const float* op      = (const float*)d_in[0];
    const float* ma      = (const float*)d_in[1];
    const float* eg      = (const float*)d_in[2];
    const int*   ma_adj  = (const int*)d_in[3];
    const int*   pre_adj = (const int*)d_in[4];
    const int*   sub_adj = (const int*)d_in[5];
    const int*   bidx    = (const int*)d_in[6];
    const float* attn    = (const float*)d_in[7];
    float* out = (float*)d_out;
    const float* Wraw[5][6];
    for (int m = 0; m < 5; ++m)
        for (int j = 0; j < 6; ++j)
            Wraw[m][j] = (const float*)d_in[8 + 6 * m + j];

    // ---- workspace layout ----
    float* wsf = (float*)d_ws;
    float* pre_agg = wsf;  wsf += (size_t)NROW * 16;
    float* sub_agg = wsf;  wsf += (size_t)NROW * 16;
    float* pre_f1  = wsf;  wsf += (size_t)NROW * OUTc;
    float* sub_f1  = wsf;  wsf += (size_t)NROW * OUTc;
    float* self_f1 = wsf;  wsf += (size_t)NROW * OUTc;
    float* ma_f2   = wsf;  wsf += (size_t)NROW * OUTc;
    float* uts     = wsf;  wsf += (size_t)4 * NROW;
    float* f1z     = wsf;  wsf += 128;
    float* sumG    = wsf;  wsf += (size_t)NROW * 128;
    int*   counts  = (int*)wsf;   wsf += NROW;
    int*   bases   = (int*)wsf;   wsf += NROW;
    int*   natot   = (int*)wsf;   wsf += 16;
    ush*   rowseg  = (ush*)wsf;   wsf += NEMAX / 2;
    ush*   Xq      = (ush*)wsf;   wsf += (size_t)NEMAX * 8;   // NEMAX rows * 16 ush
    ush*   packp   = (ush*)wsf;

    PrepArgs pa;
    MlpPack pk[5];
    for (int m = 0; m < 5; ++m) {
        const int kre[3] = { (m == 4 ? 128 : 16), 256, 256 };
        const int kbn[3] = { (m == 4 ? 4 : 1), 8, 8 };
        const int nbn[3] = { 16, 16, 8 };
        const ush* dh[3]; const ush* dl[3];
        for (int j = 0; j < 3; ++j) {
            const int id = m * 3 + j;
            pa.d[id].src = Wraw[m][2 * j];
            pa.d[id].kreal = kre[j];
            pa.d[id].kbn = kbn[j];
            pa.d[id].nbn = nbn[j];
            const int cnt = kbn[j] * nbn[j] * 512;
            pa.d[id].dh = packp; dh[j] = packp; packp += cnt;
            pa.d[id].dl = packp; dl[j] = packp; packp += cnt;
        }
        pk[m].w1h = dh[0]; pk[m].w1l = dl[0];
        pk[m].w2h = dh[1]; pk[m].w2l = dl[1];
        pk[m].w3h = dh[2]; pk[m].w3l = dl[2];
        pk[m].b1 = Wraw[m][1]; pk[m].b2 = Wraw[m][3]; pk[m].b3 = Wraw[m][5];
    }
    pa.op = op; pa.pre_adj = pre_adj; pa.sub_adj = sub_adj; pa.ma_adj = ma_adj;
    pa.bidx = bidx;
    pa.pre_agg = pre_agg; pa.sub_agg = sub_agg;
    pa.z_b1 = Wraw[0][1]; pa.z_w2 = Wraw[0][2]; pa.z_b2 = Wraw[0][3];
    pa.z_w3 = Wraw[0][4]; pa.z_b3 = Wraw[0][5];
    pa.f1z = f1z;
    pa.ma = ma; pa.eg = eg; pa.bases = bases;
    pa.Xq = Xq; pa.rowseg = rowseg; pa.sumG = sumG;

    EF1Args ea;
    ea.Xq = Xq; ea.rowseg = rowseg; ea.natot = natot; ea.P0 = pk[0];
    ea.sumG = sumG;
    ea.X[0] = pre_agg; ea.X[1] = sub_agg; ea.X[2] = op;
    ea.P[0] = pk[1];   ea.P[1] = pk[2];   ea.P[2] = pk[3];
    ea.f1[0] = pre_f1; ea.f1[1] = sub_f1; ea.f1[2] = self_f1;
    ea.ut[0] = uts + 0 * NROW;
    ea.ut[1] = uts + 1 * NROW;
    ea.ut[2] = uts + 2 * NROW;

    count_kernel<<<dim3(NROW / 4), 256, 0, stream>>>(ma_adj, bidx, counts);
    scan_kernel<<<1, 1024, 0, stream>>>(counts, bases, natot, Xq, rowseg);
    prep_kernel<<<dim3(960 + 128 + 1 + NROW / 4), 256, 0, stream>>>(pa);
    edge_f1_kernel<<<dim3(8192 + 768), 256, 0, stream>>>(ea, attn);
    p3_kernel<<<dim3(256), 256, 0, stream>>>(pk[4], attn, sumG, counts, f1z,
                                             ma_f2, uts + 3 * NROW);
    combine2_kernel<<<dim3(NBb * 16), 256, 0, stream>>>(uts, pre_f1, sub_f1, self_f1, ma_f2, out);
}